// Round 1
// baseline (1876.497 us; speedup 1.0000x reference)
//
#include <hip/hip_runtime.h>
#include <hip/hip_bf16.h>
#include <math.h>

// GAT layer: N=100000 nodes, E=1600000 edges, F_IN=F_HID=F_OUT=64, H=4 heads (Dh=16).
// Inputs: h[N,64] f32, src[E] i32, dst[E] i32, Wk[64,64], Wq[64,64], W[64,64], b[64], num_heads(=4)
// Output: [N, 256] f32  (row n = [head0 f0..63, head1 f0..63, ...])

#define FDIM 64
#define NHEADS 4
#define DH 16

// K1: k = h @ Wk, q = h @ Wq.  One wave per node row; lane j computes col j.
__global__ __launch_bounds__(256) void kq_kernel(
    const float* __restrict__ h, const float* __restrict__ Wk,
    const float* __restrict__ Wq, float* __restrict__ k, float* __restrict__ q, int N)
{
    __shared__ float sWk[FDIM * FDIM];
    __shared__ float sWq[FDIM * FDIM];
    for (int i = threadIdx.x; i < FDIM * FDIM; i += 256) {
        sWk[i] = Wk[i];
        sWq[i] = Wq[i];
    }
    __syncthreads();
    int j  = threadIdx.x & 63;
    int rl = threadIdx.x >> 6;
    int n  = blockIdx.x * 4 + rl;
    if (n >= N) return;
    const float* hrow = h + (size_t)n * FDIM;
    float acck = 0.f, accq = 0.f;
#pragma unroll 16
    for (int f = 0; f < FDIM; ++f) {
        float hv = hrow[f];  // wave-uniform broadcast load
        acck = fmaf(hv, sWk[f * FDIM + j], acck);
        accq = fmaf(hv, sWq[f * FDIM + j], accq);
    }
    k[(size_t)n * FDIM + j] = acck;
    q[(size_t)n * FDIM + j] = accq;
}

// K2: per (edge, head): e = <k[src], q[dst]> over 16 dims; ex = exp(e); z[dst,h] += ex.
// No max-subtraction: |e| <= ~25 in practice, exp stays far below fp32 overflow.
__global__ __launch_bounds__(256) void score_kernel(
    const int* __restrict__ src, const int* __restrict__ dst,
    const float* __restrict__ k, const float* __restrict__ q,
    float* __restrict__ ex, float* __restrict__ z, int E)
{
    int t = blockIdx.x * 256 + threadIdx.x;
    if (t >= E * NHEADS) return;
    int e  = t >> 2;
    int hh = t & 3;
    int s = src[e];
    int d = dst[e];
    const float4* kr = (const float4*)(k + (size_t)s * FDIM + hh * DH);
    const float4* qr = (const float4*)(q + (size_t)d * FDIM + hh * DH);
    float acc = 0.f;
#pragma unroll
    for (int i = 0; i < 4; ++i) {
        float4 a = kr[i];
        float4 bq = qr[i];
        acc += a.x * bq.x + a.y * bq.y + a.z * bq.z + a.w * bq.w;
    }
    float exv = expf(acc);
    ex[t] = exv;
    atomicAdd(&z[(size_t)d * NHEADS + hh], exv);
}

// K3: wave per edge (grid-stride). Lane f loads h[src][f]; for each head,
// w = ex/z (wave-uniform), atomicAdd into hn[dst][head][f].
__global__ __launch_bounds__(256) void aggregate_kernel(
    const int* __restrict__ src, const int* __restrict__ dst,
    const float* __restrict__ h, const float* __restrict__ ex,
    const float* __restrict__ z, float* __restrict__ hn, int E)
{
    int lane   = threadIdx.x & 63;
    int warp   = blockIdx.x * 4 + (threadIdx.x >> 6);
    int nwarps = gridDim.x * 4;
    for (int e = warp; e < E; e += nwarps) {
        int s = src[e];
        int d = dst[e];
        float hv = h[(size_t)s * FDIM + lane];
        float* outrow = hn + (size_t)d * (NHEADS * FDIM);
#pragma unroll
        for (int hh = 0; hh < NHEADS; ++hh) {
            float w = ex[(size_t)e * NHEADS + hh] / z[(size_t)d * NHEADS + hh];
            atomicAdd(&outrow[hh * FDIM + lane], w * hv);
        }
    }
}

// K4: out = hn @ W + b over R = N*H rows of 64.
__global__ __launch_bounds__(256) void out_kernel(
    const float* __restrict__ hn, const float* __restrict__ W,
    const float* __restrict__ b, float* __restrict__ out, int R)
{
    __shared__ float sW[FDIM * FDIM];
    __shared__ float sb[FDIM];
    for (int i = threadIdx.x; i < FDIM * FDIM; i += 256) sW[i] = W[i];
    if (threadIdx.x < FDIM) sb[threadIdx.x] = b[threadIdx.x];
    __syncthreads();
    int j  = threadIdx.x & 63;
    int rl = threadIdx.x >> 6;
    int r  = blockIdx.x * 4 + rl;
    if (r >= R) return;
    const float* row = hn + (size_t)r * FDIM;
    float acc = sb[j];
#pragma unroll 16
    for (int f = 0; f < FDIM; ++f)
        acc = fmaf(row[f], sW[f * FDIM + j], acc);
    out[(size_t)r * FDIM + j] = acc;
}

extern "C" void kernel_launch(void* const* d_in, const int* in_sizes, int n_in,
                              void* d_out, int out_size, void* d_ws, size_t ws_size,
                              hipStream_t stream) {
    const float* h   = (const float*)d_in[0];
    const int*   src = (const int*)d_in[1];
    const int*   dst = (const int*)d_in[2];
    const float* Wk  = (const float*)d_in[3];
    const float* Wq  = (const float*)d_in[4];
    const float* W   = (const float*)d_in[5];
    const float* b   = (const float*)d_in[6];
    float* out = (float*)d_out;

    const int N = in_sizes[0] / FDIM;   // 100000
    const int E = in_sizes[1];          // 1600000

    // Workspace layout (floats):
    float* ws = (float*)d_ws;
    float* k  = ws;                              // N*64
    float* q  = k + (size_t)N * FDIM;            // N*64
    float* ex = q + (size_t)N * FDIM;            // E*4
    float* z  = ex + (size_t)E * NHEADS;         // N*4
    float* hn = z + (size_t)N * NHEADS;          // N*256

    hipMemsetAsync(z, 0, (size_t)N * NHEADS * sizeof(float), stream);
    hipMemsetAsync(hn, 0, (size_t)N * NHEADS * FDIM * sizeof(float), stream);

    kq_kernel<<<(N + 3) / 4, 256, 0, stream>>>(h, Wk, Wq, k, q, N);
    score_kernel<<<(E * NHEADS + 255) / 256, 256, 0, stream>>>(src, dst, k, q, ex, z, E);
    aggregate_kernel<<<4096, 256, 0, stream>>>(src, dst, h, ex, z, hn, E);
    out_kernel<<<(N * NHEADS + 3) / 4, 256, 0, stream>>>(hn, W, b, out, N * NHEADS);
}

// Round 2
// 882.211 us; speedup vs baseline: 2.1270x; 2.1270x over previous
//
#include <hip/hip_runtime.h>
#include <math.h>

// GAT layer: N=100000, E=1600000, F=64, H=4 (Dh=16). fp32 throughout.
// Strategy: counting-sort edges by dst -> CSR, then atomic-free gather aggregation.

#define FDIM 64
#define NHEADS 4

// K1: k = h @ Wk, q = h @ Wq.  One wave per node row; lane j computes col j.
__global__ __launch_bounds__(256) void kq_kernel(
    const float* __restrict__ h, const float* __restrict__ Wk,
    const float* __restrict__ Wq, float* __restrict__ k, float* __restrict__ q, int N)
{
    __shared__ float sWk[FDIM * FDIM];
    __shared__ float sWq[FDIM * FDIM];
    for (int i = threadIdx.x; i < FDIM * FDIM; i += 256) {
        sWk[i] = Wk[i];
        sWq[i] = Wq[i];
    }
    __syncthreads();
    int j  = threadIdx.x & 63;
    int rl = threadIdx.x >> 6;
    int n  = blockIdx.x * 4 + rl;
    if (n >= N) return;
    const float* hrow = h + (size_t)n * FDIM;
    float acck = 0.f, accq = 0.f;
#pragma unroll 16
    for (int f = 0; f < FDIM; ++f) {
        float hv = hrow[f];
        acck = fmaf(hv, sWk[f * FDIM + j], acck);
        accq = fmaf(hv, sWq[f * FDIM + j], accq);
    }
    k[(size_t)n * FDIM + j] = acck;
    q[(size_t)n * FDIM + j] = accq;
}

// K2: histogram of in-degrees.
__global__ __launch_bounds__(256) void hist_kernel(
    const int* __restrict__ dst, int* __restrict__ counts, int E)
{
    int e = blockIdx.x * 256 + threadIdx.x;
    if (e < E) atomicAdd(&counts[dst[e]], 1);
}

// K3a: per-1024-chunk exclusive scan of counts -> rowptr (local), block totals -> bsum.
__global__ __launch_bounds__(256) void scan1_kernel(
    const int* __restrict__ counts, int* __restrict__ rowptr,
    int* __restrict__ bsum, int N)
{
    __shared__ int sd[256];
    int base = blockIdx.x * 1024;
    int t = threadIdx.x;
    int c[4];
    int s = 0;
#pragma unroll
    for (int i = 0; i < 4; ++i) {
        int idx = base + t * 4 + i;
        c[i] = (idx < N) ? counts[idx] : 0;
        s += c[i];
    }
    sd[t] = s;
    __syncthreads();
    for (int off = 1; off < 256; off <<= 1) {
        int v = (t >= off) ? sd[t - off] : 0;
        __syncthreads();
        sd[t] += v;
        __syncthreads();
    }
    int ex = sd[t] - s;  // exclusive prefix within chunk
#pragma unroll
    for (int i = 0; i < 4; ++i) {
        int idx = base + t * 4 + i;
        if (idx < N) rowptr[idx] = ex;
        ex += c[i];
    }
    if (t == 255) bsum[blockIdx.x] = sd[255];
}

// K3b: single-block exclusive scan of bsum (NBLK <= 256).
__global__ __launch_bounds__(256) void scan2_kernel(int* __restrict__ bsum, int NBLK)
{
    __shared__ int sd[256];
    int t = threadIdx.x;
    int v = (t < NBLK) ? bsum[t] : 0;
    sd[t] = v;
    __syncthreads();
    for (int off = 1; off < 256; off <<= 1) {
        int u = (t >= off) ? sd[t - off] : 0;
        __syncthreads();
        sd[t] += u;
        __syncthreads();
    }
    if (t < NBLK) bsum[t] = sd[t] - v;
}

// K3c: add chunk offsets.
__global__ __launch_bounds__(256) void scan3_kernel(
    int* __restrict__ rowptr, const int* __restrict__ bsum, int N)
{
    int i = blockIdx.x * 256 + threadIdx.x;
    if (i < N) rowptr[i] += bsum[i >> 10];
}

// K4: scatter edges into dst-sorted order. rowptr becomes rowend afterwards.
__global__ __launch_bounds__(256) void scatter_kernel(
    const int* __restrict__ src, const int* __restrict__ dst,
    int* __restrict__ rowptr, int* __restrict__ ssorted, int* __restrict__ pos, int E)
{
    int e = blockIdx.x * 256 + threadIdx.x;
    if (e >= E) return;
    int p = atomicAdd(&rowptr[dst[e]], 1);
    pos[e] = p;
    ssorted[p] = src[e];
}

// K5: per (edge, head): e = <k[src], q[dst]>; write exp(e) to sorted slot.
// No max-subtraction: |e| <~ 25, exp stays far below fp32 overflow; a = ex/z is
// scale-invariant so result matches the max-subtracted reference to fp32 rounding.
__global__ __launch_bounds__(256) void score_kernel(
    const int* __restrict__ src, const int* __restrict__ dst,
    const int* __restrict__ pos, const float* __restrict__ k,
    const float* __restrict__ q, float* __restrict__ exs, int E)
{
    int t = blockIdx.x * 256 + threadIdx.x;
    if (t >= E * NHEADS) return;
    int e  = t >> 2;
    int hh = t & 3;
    int s = src[e];
    int d = dst[e];
    const float4* kr = (const float4*)(k + (size_t)s * FDIM + hh * 16);
    const float4* qr = (const float4*)(q + (size_t)d * FDIM + hh * 16);
    float acc = 0.f;
#pragma unroll
    for (int i = 0; i < 4; ++i) {
        float4 a  = kr[i];
        float4 bq = qr[i];
        acc += a.x * bq.x + a.y * bq.y + a.z * bq.z + a.w * bq.w;
    }
    exs[(size_t)pos[e] * NHEADS + hh] = expf(acc);
}

// K6: gather aggregation. One wave per node; lane = feature. Accumulates
// acc_h = sum(ex*h[src]) and z_h = sum(ex) in registers; divides once at end.
__global__ __launch_bounds__(256) void aggregate_kernel(
    const int* __restrict__ rowend, const int* __restrict__ counts,
    const int* __restrict__ ssorted, const float* __restrict__ exs,
    const float* __restrict__ h, float* __restrict__ hn, int N)
{
    int lane = threadIdx.x & 63;
    int n = blockIdx.x * 4 + (threadIdx.x >> 6);
    if (n >= N) return;
    int end = rowend[n];
    int cnt = counts[n];
    int start = end - cnt;
    const float4* exs4 = (const float4*)exs;
    float a0 = 0.f, a1 = 0.f, a2 = 0.f, a3 = 0.f;
    float z0 = 0.f, z1 = 0.f, z2 = 0.f, z3 = 0.f;
    int i = start;
    for (; i + 1 < end; i += 2) {
        int s0 = ssorted[i];
        int s1 = ssorted[i + 1];
        float4 e0 = exs4[i];
        float4 e1 = exs4[i + 1];
        float hv0 = h[(size_t)s0 * FDIM + lane];
        float hv1 = h[(size_t)s1 * FDIM + lane];
        a0 = fmaf(e0.x, hv0, a0); a1 = fmaf(e0.y, hv0, a1);
        a2 = fmaf(e0.z, hv0, a2); a3 = fmaf(e0.w, hv0, a3);
        z0 += e0.x; z1 += e0.y; z2 += e0.z; z3 += e0.w;
        a0 = fmaf(e1.x, hv1, a0); a1 = fmaf(e1.y, hv1, a1);
        a2 = fmaf(e1.z, hv1, a2); a3 = fmaf(e1.w, hv1, a3);
        z0 += e1.x; z1 += e1.y; z2 += e1.z; z3 += e1.w;
    }
    if (i < end) {
        int s0 = ssorted[i];
        float4 e0 = exs4[i];
        float hv0 = h[(size_t)s0 * FDIM + lane];
        a0 = fmaf(e0.x, hv0, a0); a1 = fmaf(e0.y, hv0, a1);
        a2 = fmaf(e0.z, hv0, a2); a3 = fmaf(e0.w, hv0, a3);
        z0 += e0.x; z1 += e0.y; z2 += e0.z; z3 += e0.w;
    }
    float* outr = hn + (size_t)n * (NHEADS * FDIM);
    if (cnt > 0) {
        outr[lane]             = a0 / z0;
        outr[FDIM + lane]      = a1 / z1;
        outr[2 * FDIM + lane]  = a2 / z2;
        outr[3 * FDIM + lane]  = a3 / z3;
    } else {
        outr[lane] = 0.f;
        outr[FDIM + lane] = 0.f;
        outr[2 * FDIM + lane] = 0.f;
        outr[3 * FDIM + lane] = 0.f;
    }
}

// K7: out = hn @ W + b over R = N*H rows of 64.
__global__ __launch_bounds__(256) void out_kernel(
    const float* __restrict__ hn, const float* __restrict__ W,
    const float* __restrict__ b, float* __restrict__ out, int R)
{
    __shared__ float sW[FDIM * FDIM];
    __shared__ float sb[FDIM];
    for (int i = threadIdx.x; i < FDIM * FDIM; i += 256) sW[i] = W[i];
    if (threadIdx.x < FDIM) sb[threadIdx.x] = b[threadIdx.x];
    __syncthreads();
    int j  = threadIdx.x & 63;
    int rl = threadIdx.x >> 6;
    int r  = blockIdx.x * 4 + rl;
    if (r >= R) return;
    const float* row = hn + (size_t)r * FDIM;
    float acc = sb[j];
#pragma unroll 16
    for (int f = 0; f < FDIM; ++f)
        acc = fmaf(row[f], sW[f * FDIM + j], acc);
    out[(size_t)r * FDIM + j] = acc;
}

extern "C" void kernel_launch(void* const* d_in, const int* in_sizes, int n_in,
                              void* d_out, int out_size, void* d_ws, size_t ws_size,
                              hipStream_t stream) {
    const float* h   = (const float*)d_in[0];
    const int*   src = (const int*)d_in[1];
    const int*   dst = (const int*)d_in[2];
    const float* Wk  = (const float*)d_in[3];
    const float* Wq  = (const float*)d_in[4];
    const float* W   = (const float*)d_in[5];
    const float* b   = (const float*)d_in[6];
    float* out = (float*)d_out;

    const int N = in_sizes[0] / FDIM;   // 100000
    const int E = in_sizes[1];          // 1600000

    // Workspace layout (4B words). hn aliases k,q (k,q dead before hn written).
    //   [0 .. N*64)        k          (later clobbered by hn)
    //   [N*64 .. N*128)    q          (later clobbered by hn)
    //   [0 .. N*256)       hn
    //   [N*256 ...)        exs[E*4], ssorted[E], pos[E], counts[N], rowptr[N], bsum[256]
    float* ws = (float*)d_ws;
    float* hn  = ws;
    float* k   = ws;
    float* q   = ws + (size_t)N * FDIM;
    float* exs = ws + (size_t)N * (NHEADS * FDIM);
    int* ssorted = (int*)(exs + (size_t)E * NHEADS);
    int* pos     = ssorted + E;
    int* counts  = pos + E;
    int* rowptr  = counts + N;
    int* bsum    = rowptr + N;

    const int NBLK = (N + 1023) / 1024;  // 98

    hipMemsetAsync(counts, 0, (size_t)N * sizeof(int), stream);

    kq_kernel<<<(N + 3) / 4, 256, 0, stream>>>(h, Wk, Wq, k, q, N);
    hist_kernel<<<(E + 255) / 256, 256, 0, stream>>>(dst, counts, E);
    scan1_kernel<<<NBLK, 256, 0, stream>>>(counts, rowptr, bsum, N);
    scan2_kernel<<<1, 256, 0, stream>>>(bsum, NBLK);
    scan3_kernel<<<(N + 255) / 256, 256, 0, stream>>>(rowptr, bsum, N);
    scatter_kernel<<<(E + 255) / 256, 256, 0, stream>>>(src, dst, rowptr, ssorted, pos, E);
    score_kernel<<<(E * NHEADS + 255) / 256, 256, 0, stream>>>(src, dst, pos, k, q, exs, E);
    aggregate_kernel<<<(N + 3) / 4, 256, 0, stream>>>(rowptr, counts, ssorted, exs, h, hn, N);
    out_kernel<<<(N * NHEADS + 3) / 4, 256, 0, stream>>>(hn, W, b, out, N * NHEADS);
}

// Round 3
// 671.979 us; speedup vs baseline: 2.7925x; 1.3129x over previous
//
#include <hip/hip_runtime.h>
#include <math.h>

// GAT layer: N=100000, E=1600000, F=64, H=4 (Dh=16). fp32 throughout.
// Counting-sort edges by dst -> CSR, atomic-free gather aggregation,
// register-blocked dense GEMMs for projections.

#define FDIM 64
#define NHEADS 4

// K1: k = h @ Wk, q = h @ Wq. Thread = 2 rows x 16 cols x 2 matrices (64 acc).
// Block = 256 threads -> 128 rows.
__global__ __launch_bounds__(256) void kq_kernel(
    const float* __restrict__ h, const float* __restrict__ Wk,
    const float* __restrict__ Wq, float* __restrict__ k, float* __restrict__ q, int N)
{
    __shared__ float sWk[FDIM * FDIM];
    __shared__ float sWq[FDIM * FDIM];
    for (int i = threadIdx.x; i < FDIM * FDIM; i += 256) {
        sWk[i] = Wk[i];
        sWq[i] = Wq[i];
    }
    __syncthreads();
    int cg = threadIdx.x & 3;    // col group: cols cg*16 .. cg*16+15
    int rg = threadIdx.x >> 2;   // 0..63 -> 2 rows each
    long base = (long)blockIdx.x * 128 + rg * 2;
    const float4* sWk4 = (const float4*)sWk;
    const float4* sWq4 = (const float4*)sWq;
    const float4* h4 = (const float4*)h;
    float acck[2][16], accq[2][16];
#pragma unroll
    for (int i = 0; i < 2; ++i)
#pragma unroll
        for (int c = 0; c < 16; ++c) { acck[i][c] = 0.f; accq[i][c] = 0.f; }

    for (int fs = 0; fs < FDIM; fs += 4) {
        float4 hv[2];
#pragma unroll
        for (int i = 0; i < 2; ++i) {
            long r = base + i; if (r >= N) r = N - 1;
            hv[i] = h4[r * 16 + (fs >> 2)];
        }
#pragma unroll
        for (int fi = 0; fi < 4; ++fi) {
            int f = fs + fi;
            float4 wk0 = sWk4[f * 16 + cg * 4 + 0];
            float4 wk1 = sWk4[f * 16 + cg * 4 + 1];
            float4 wk2 = sWk4[f * 16 + cg * 4 + 2];
            float4 wk3 = sWk4[f * 16 + cg * 4 + 3];
            float4 wq0 = sWq4[f * 16 + cg * 4 + 0];
            float4 wq1 = sWq4[f * 16 + cg * 4 + 1];
            float4 wq2 = sWq4[f * 16 + cg * 4 + 2];
            float4 wq3 = sWq4[f * 16 + cg * 4 + 3];
#pragma unroll
            for (int i = 0; i < 2; ++i) {
                float hvf = (&hv[i].x)[fi];
                acck[i][0]  = fmaf(hvf, wk0.x, acck[i][0]);
                acck[i][1]  = fmaf(hvf, wk0.y, acck[i][1]);
                acck[i][2]  = fmaf(hvf, wk0.z, acck[i][2]);
                acck[i][3]  = fmaf(hvf, wk0.w, acck[i][3]);
                acck[i][4]  = fmaf(hvf, wk1.x, acck[i][4]);
                acck[i][5]  = fmaf(hvf, wk1.y, acck[i][5]);
                acck[i][6]  = fmaf(hvf, wk1.z, acck[i][6]);
                acck[i][7]  = fmaf(hvf, wk1.w, acck[i][7]);
                acck[i][8]  = fmaf(hvf, wk2.x, acck[i][8]);
                acck[i][9]  = fmaf(hvf, wk2.y, acck[i][9]);
                acck[i][10] = fmaf(hvf, wk2.z, acck[i][10]);
                acck[i][11] = fmaf(hvf, wk2.w, acck[i][11]);
                acck[i][12] = fmaf(hvf, wk3.x, acck[i][12]);
                acck[i][13] = fmaf(hvf, wk3.y, acck[i][13]);
                acck[i][14] = fmaf(hvf, wk3.z, acck[i][14]);
                acck[i][15] = fmaf(hvf, wk3.w, acck[i][15]);
                accq[i][0]  = fmaf(hvf, wq0.x, accq[i][0]);
                accq[i][1]  = fmaf(hvf, wq0.y, accq[i][1]);
                accq[i][2]  = fmaf(hvf, wq0.z, accq[i][2]);
                accq[i][3]  = fmaf(hvf, wq0.w, accq[i][3]);
                accq[i][4]  = fmaf(hvf, wq1.x, accq[i][4]);
                accq[i][5]  = fmaf(hvf, wq1.y, accq[i][5]);
                accq[i][6]  = fmaf(hvf, wq1.z, accq[i][6]);
                accq[i][7]  = fmaf(hvf, wq1.w, accq[i][7]);
                accq[i][8]  = fmaf(hvf, wq2.x, accq[i][8]);
                accq[i][9]  = fmaf(hvf, wq2.y, accq[i][9]);
                accq[i][10] = fmaf(hvf, wq2.z, accq[i][10]);
                accq[i][11] = fmaf(hvf, wq2.w, accq[i][11]);
                accq[i][12] = fmaf(hvf, wq3.x, accq[i][12]);
                accq[i][13] = fmaf(hvf, wq3.y, accq[i][13]);
                accq[i][14] = fmaf(hvf, wq3.z, accq[i][14]);
                accq[i][15] = fmaf(hvf, wq3.w, accq[i][15]);
            }
        }
    }
#pragma unroll
    for (int i = 0; i < 2; ++i) {
        long r = base + i;
        if (r >= N) continue;
        float4* kout = (float4*)(k + (size_t)r * FDIM + cg * 16);
        float4* qout = (float4*)(q + (size_t)r * FDIM + cg * 16);
#pragma unroll
        for (int c4 = 0; c4 < 4; ++c4) {
            kout[c4] = make_float4(acck[i][c4*4], acck[i][c4*4+1], acck[i][c4*4+2], acck[i][c4*4+3]);
            qout[c4] = make_float4(accq[i][c4*4], accq[i][c4*4+1], accq[i][c4*4+2], accq[i][c4*4+3]);
        }
    }
}

// K2: histogram of in-degrees.
__global__ __launch_bounds__(256) void hist_kernel(
    const int* __restrict__ dst, int* __restrict__ counts, int E)
{
    int e = blockIdx.x * 256 + threadIdx.x;
    if (e < E) atomicAdd(&counts[dst[e]], 1);
}

// K3a: per-1024-chunk exclusive scan of counts -> rowptr (local), block totals -> bsum.
__global__ __launch_bounds__(256) void scan1_kernel(
    const int* __restrict__ counts, int* __restrict__ rowptr,
    int* __restrict__ bsum, int N)
{
    __shared__ int sd[256];
    int base = blockIdx.x * 1024;
    int t = threadIdx.x;
    int c[4];
    int s = 0;
#pragma unroll
    for (int i = 0; i < 4; ++i) {
        int idx = base + t * 4 + i;
        c[i] = (idx < N) ? counts[idx] : 0;
        s += c[i];
    }
    sd[t] = s;
    __syncthreads();
    for (int off = 1; off < 256; off <<= 1) {
        int v = (t >= off) ? sd[t - off] : 0;
        __syncthreads();
        sd[t] += v;
        __syncthreads();
    }
    int ex = sd[t] - s;
#pragma unroll
    for (int i = 0; i < 4; ++i) {
        int idx = base + t * 4 + i;
        if (idx < N) rowptr[idx] = ex;
        ex += c[i];
    }
    if (t == 255) bsum[blockIdx.x] = sd[255];
}

// K3b: single-block exclusive scan of bsum (NBLK <= 256).
__global__ __launch_bounds__(256) void scan2_kernel(int* __restrict__ bsum, int NBLK)
{
    __shared__ int sd[256];
    int t = threadIdx.x;
    int v = (t < NBLK) ? bsum[t] : 0;
    sd[t] = v;
    __syncthreads();
    for (int off = 1; off < 256; off <<= 1) {
        int u = (t >= off) ? sd[t - off] : 0;
        __syncthreads();
        sd[t] += u;
        __syncthreads();
    }
    if (t < NBLK) bsum[t] = sd[t] - v;
}

// K3c: add chunk offsets.
__global__ __launch_bounds__(256) void scan3_kernel(
    int* __restrict__ rowptr, const int* __restrict__ bsum, int N)
{
    int i = blockIdx.x * 256 + threadIdx.x;
    if (i < N) rowptr[i] += bsum[i >> 10];
}

// K4: scatter edges into dst-sorted order. rowptr becomes rowend afterwards.
__global__ __launch_bounds__(256) void scatter_kernel(
    const int* __restrict__ src, const int* __restrict__ dst,
    int* __restrict__ rowptr, int* __restrict__ ssorted, int* __restrict__ pos, int E)
{
    int e = blockIdx.x * 256 + threadIdx.x;
    if (e >= E) return;
    int p = atomicAdd(&rowptr[dst[e]], 1);
    pos[e] = p;
    ssorted[p] = src[e];
}

// K5: per (edge, head): e = <k[src], q[dst]>; write exp(e) to sorted slot.
// No max-subtraction: |e| <~ 25, exp stays far below fp32 overflow; a = ex/z is
// scale-invariant so result matches the max-subtracted reference to fp32 rounding.
__global__ __launch_bounds__(256) void score_kernel(
    const int* __restrict__ src, const int* __restrict__ dst,
    const int* __restrict__ pos, const float* __restrict__ k,
    const float* __restrict__ q, float* __restrict__ exs, int E)
{
    int t = blockIdx.x * 256 + threadIdx.x;
    if (t >= E * NHEADS) return;
    int e  = t >> 2;
    int hh = t & 3;
    int s = src[e];
    int d = dst[e];
    const float4* kr = (const float4*)(k + (size_t)s * FDIM + hh * 16);
    const float4* qr = (const float4*)(q + (size_t)d * FDIM + hh * 16);
    float acc = 0.f;
#pragma unroll
    for (int i = 0; i < 4; ++i) {
        float4 a  = kr[i];
        float4 bq = qr[i];
        acc += a.x * bq.x + a.y * bq.y + a.z * bq.z + a.w * bq.w;
    }
    exs[(size_t)pos[e] * NHEADS + hh] = expf(acc);
}

// K6: gather aggregation. One wave per node; lane = feature.
__global__ __launch_bounds__(256) void aggregate_kernel(
    const int* __restrict__ rowend, const int* __restrict__ counts,
    const int* __restrict__ ssorted, const float* __restrict__ exs,
    const float* __restrict__ h, float* __restrict__ hn, int N)
{
    int lane = threadIdx.x & 63;
    int n = blockIdx.x * 4 + (threadIdx.x >> 6);
    if (n >= N) return;
    int end = rowend[n];
    int cnt = counts[n];
    int start = end - cnt;
    const float4* exs4 = (const float4*)exs;
    float a0 = 0.f, a1 = 0.f, a2 = 0.f, a3 = 0.f;
    float z0 = 0.f, z1 = 0.f, z2 = 0.f, z3 = 0.f;
    int i = start;
    for (; i + 1 < end; i += 2) {
        int s0 = ssorted[i];
        int s1 = ssorted[i + 1];
        float4 e0 = exs4[i];
        float4 e1 = exs4[i + 1];
        float hv0 = h[(size_t)s0 * FDIM + lane];
        float hv1 = h[(size_t)s1 * FDIM + lane];
        a0 = fmaf(e0.x, hv0, a0); a1 = fmaf(e0.y, hv0, a1);
        a2 = fmaf(e0.z, hv0, a2); a3 = fmaf(e0.w, hv0, a3);
        z0 += e0.x; z1 += e0.y; z2 += e0.z; z3 += e0.w;
        a0 = fmaf(e1.x, hv1, a0); a1 = fmaf(e1.y, hv1, a1);
        a2 = fmaf(e1.z, hv1, a2); a3 = fmaf(e1.w, hv1, a3);
        z0 += e1.x; z1 += e1.y; z2 += e1.z; z3 += e1.w;
    }
    if (i < end) {
        int s0 = ssorted[i];
        float4 e0 = exs4[i];
        float hv0 = h[(size_t)s0 * FDIM + lane];
        a0 = fmaf(e0.x, hv0, a0); a1 = fmaf(e0.y, hv0, a1);
        a2 = fmaf(e0.z, hv0, a2); a3 = fmaf(e0.w, hv0, a3);
        z0 += e0.x; z1 += e0.y; z2 += e0.z; z3 += e0.w;
    }
    float* outr = hn + (size_t)n * (NHEADS * FDIM);
    if (cnt > 0) {
        outr[lane]             = a0 / z0;
        outr[FDIM + lane]      = a1 / z1;
        outr[2 * FDIM + lane]  = a2 / z2;
        outr[3 * FDIM + lane]  = a3 / z3;
    } else {
        outr[lane] = 0.f;
        outr[FDIM + lane] = 0.f;
        outr[2 * FDIM + lane] = 0.f;
        outr[3 * FDIM + lane] = 0.f;
    }
}

// K7: out = hn @ W + b. Thread = 4 rows x 16 cols (64 acc). Block = 256 rows.
__global__ __launch_bounds__(256) void out_kernel(
    const float* __restrict__ hn, const float* __restrict__ W,
    const float* __restrict__ b, float* __restrict__ out, int R)
{
    __shared__ float sW[FDIM * FDIM];
    __shared__ float sb[FDIM];
    for (int i = threadIdx.x; i < FDIM * FDIM; i += 256) sW[i] = W[i];
    if (threadIdx.x < FDIM) sb[threadIdx.x] = b[threadIdx.x];
    __syncthreads();
    int cg = threadIdx.x & 3;
    int rg = threadIdx.x >> 2;
    long base = (long)blockIdx.x * 256 + rg * 4;
    const float4* sW4 = (const float4*)sW;
    const float4* hn4 = (const float4*)hn;
    float acc[4][16];
#pragma unroll
    for (int i = 0; i < 4; ++i)
#pragma unroll
        for (int c = 0; c < 16; ++c) acc[i][c] = sb[cg * 16 + c];

    for (int fs = 0; fs < FDIM; fs += 4) {
        float4 hv[4];
#pragma unroll
        for (int i = 0; i < 4; ++i) {
            long r = base + i; if (r >= R) r = R - 1;
            hv[i] = hn4[r * 16 + (fs >> 2)];
        }
#pragma unroll
        for (int fi = 0; fi < 4; ++fi) {
            int f = fs + fi;
            float4 w0 = sW4[f * 16 + cg * 4 + 0];
            float4 w1 = sW4[f * 16 + cg * 4 + 1];
            float4 w2 = sW4[f * 16 + cg * 4 + 2];
            float4 w3 = sW4[f * 16 + cg * 4 + 3];
#pragma unroll
            for (int i = 0; i < 4; ++i) {
                float hvf = (&hv[i].x)[fi];
                acc[i][0]  = fmaf(hvf, w0.x, acc[i][0]);
                acc[i][1]  = fmaf(hvf, w0.y, acc[i][1]);
                acc[i][2]  = fmaf(hvf, w0.z, acc[i][2]);
                acc[i][3]  = fmaf(hvf, w0.w, acc[i][3]);
                acc[i][4]  = fmaf(hvf, w1.x, acc[i][4]);
                acc[i][5]  = fmaf(hvf, w1.y, acc[i][5]);
                acc[i][6]  = fmaf(hvf, w1.z, acc[i][6]);
                acc[i][7]  = fmaf(hvf, w1.w, acc[i][7]);
                acc[i][8]  = fmaf(hvf, w2.x, acc[i][8]);
                acc[i][9]  = fmaf(hvf, w2.y, acc[i][9]);
                acc[i][10] = fmaf(hvf, w2.z, acc[i][10]);
                acc[i][11] = fmaf(hvf, w2.w, acc[i][11]);
                acc[i][12] = fmaf(hvf, w3.x, acc[i][12]);
                acc[i][13] = fmaf(hvf, w3.y, acc[i][13]);
                acc[i][14] = fmaf(hvf, w3.z, acc[i][14]);
                acc[i][15] = fmaf(hvf, w3.w, acc[i][15]);
            }
        }
    }
#pragma unroll
    for (int i = 0; i < 4; ++i) {
        long r = base + i;
        if (r >= R) continue;
        float4* o = (float4*)(out + (size_t)r * FDIM + cg * 16);
#pragma unroll
        for (int c4 = 0; c4 < 4; ++c4)
            o[c4] = make_float4(acc[i][c4*4], acc[i][c4*4+1], acc[i][c4*4+2], acc[i][c4*4+3]);
    }
}

extern "C" void kernel_launch(void* const* d_in, const int* in_sizes, int n_in,
                              void* d_out, int out_size, void* d_ws, size_t ws_size,
                              hipStream_t stream) {
    const float* h   = (const float*)d_in[0];
    const int*   src = (const int*)d_in[1];
    const int*   dst = (const int*)d_in[2];
    const float* Wk  = (const float*)d_in[3];
    const float* Wq  = (const float*)d_in[4];
    const float* W   = (const float*)d_in[5];
    const float* b   = (const float*)d_in[6];
    float* out = (float*)d_out;

    const int N = in_sizes[0] / FDIM;   // 100000
    const int E = in_sizes[1];          // 1600000

    // Workspace layout (4B words). hn aliases k,q (k,q dead before hn written).
    float* ws = (float*)d_ws;
    float* hn  = ws;
    float* k   = ws;
    float* q   = ws + (size_t)N * FDIM;
    float* exs = ws + (size_t)N * (NHEADS * FDIM);
    int* ssorted = (int*)(exs + (size_t)E * NHEADS);
    int* pos     = ssorted + E;
    int* counts  = pos + E;
    int* rowptr  = counts + N;
    int* bsum    = rowptr + N;

    const int NBLK = (N + 1023) / 1024;  // 98

    hipMemsetAsync(counts, 0, (size_t)N * sizeof(int), stream);

    kq_kernel<<<(N + 127) / 128, 256, 0, stream>>>(h, Wk, Wq, k, q, N);
    hist_kernel<<<(E + 255) / 256, 256, 0, stream>>>(dst, counts, E);
    scan1_kernel<<<NBLK, 256, 0, stream>>>(counts, rowptr, bsum, N);
    scan2_kernel<<<1, 256, 0, stream>>>(bsum, NBLK);
    scan3_kernel<<<(N + 255) / 256, 256, 0, stream>>>(rowptr, bsum, N);
    scatter_kernel<<<(E + 255) / 256, 256, 0, stream>>>(src, dst, rowptr, ssorted, pos, E);
    score_kernel<<<(E * NHEADS + 255) / 256, 256, 0, stream>>>(src, dst, pos, k, q, exs, E);
    aggregate_kernel<<<(N + 3) / 4, 256, 0, stream>>>(rowptr, counts, ssorted, exs, h, hn, N);
    out_kernel<<<(N * NHEADS + 255) / 256, 256, 0, stream>>>(hn, W, b, out, N * NHEADS);
}

// Round 4
// 584.993 us; speedup vs baseline: 3.2077x; 1.1487x over previous
//
#include <hip/hip_runtime.h>
#include <math.h>

// GAT layer: N=100000, E=1600000, F=64, H=4 (Dh=16). fp32 throughout.
// Pipeline: kq GEMM -> in-degree hist -> scan -> fused score+scatter
// (32B sorted records {ex0..3, src}) -> CSR gather-aggregate (writes d_out)
// -> in-place output GEMM on d_out.

#define FDIM 64
#define NHEADS 4

// K1: k = h @ Wk, q = h @ Wq. Thread = 2 rows x 16 cols x 2 matrices (64 acc).
__global__ __launch_bounds__(256) void kq_kernel(
    const float* __restrict__ h, const float* __restrict__ Wk,
    const float* __restrict__ Wq, float* __restrict__ k, float* __restrict__ q, int N)
{
    __shared__ float sWk[FDIM * FDIM];
    __shared__ float sWq[FDIM * FDIM];
    for (int i = threadIdx.x; i < FDIM * FDIM; i += 256) {
        sWk[i] = Wk[i];
        sWq[i] = Wq[i];
    }
    __syncthreads();
    int cg = threadIdx.x & 3;
    int rg = threadIdx.x >> 2;
    long base = (long)blockIdx.x * 128 + rg * 2;
    const float4* sWk4 = (const float4*)sWk;
    const float4* sWq4 = (const float4*)sWq;
    const float4* h4 = (const float4*)h;
    float acck[2][16], accq[2][16];
#pragma unroll
    for (int i = 0; i < 2; ++i)
#pragma unroll
        for (int c = 0; c < 16; ++c) { acck[i][c] = 0.f; accq[i][c] = 0.f; }

    for (int fs = 0; fs < FDIM; fs += 4) {
        float4 hv[2];
#pragma unroll
        for (int i = 0; i < 2; ++i) {
            long r = base + i; if (r >= N) r = N - 1;
            hv[i] = h4[r * 16 + (fs >> 2)];
        }
#pragma unroll
        for (int fi = 0; fi < 4; ++fi) {
            int f = fs + fi;
            float4 wk0 = sWk4[f * 16 + cg * 4 + 0];
            float4 wk1 = sWk4[f * 16 + cg * 4 + 1];
            float4 wk2 = sWk4[f * 16 + cg * 4 + 2];
            float4 wk3 = sWk4[f * 16 + cg * 4 + 3];
            float4 wq0 = sWq4[f * 16 + cg * 4 + 0];
            float4 wq1 = sWq4[f * 16 + cg * 4 + 1];
            float4 wq2 = sWq4[f * 16 + cg * 4 + 2];
            float4 wq3 = sWq4[f * 16 + cg * 4 + 3];
#pragma unroll
            for (int i = 0; i < 2; ++i) {
                float hvf = (&hv[i].x)[fi];
                acck[i][0]  = fmaf(hvf, wk0.x, acck[i][0]);
                acck[i][1]  = fmaf(hvf, wk0.y, acck[i][1]);
                acck[i][2]  = fmaf(hvf, wk0.z, acck[i][2]);
                acck[i][3]  = fmaf(hvf, wk0.w, acck[i][3]);
                acck[i][4]  = fmaf(hvf, wk1.x, acck[i][4]);
                acck[i][5]  = fmaf(hvf, wk1.y, acck[i][5]);
                acck[i][6]  = fmaf(hvf, wk1.z, acck[i][6]);
                acck[i][7]  = fmaf(hvf, wk1.w, acck[i][7]);
                acck[i][8]  = fmaf(hvf, wk2.x, acck[i][8]);
                acck[i][9]  = fmaf(hvf, wk2.y, acck[i][9]);
                acck[i][10] = fmaf(hvf, wk2.z, acck[i][10]);
                acck[i][11] = fmaf(hvf, wk2.w, acck[i][11]);
                acck[i][12] = fmaf(hvf, wk3.x, acck[i][12]);
                acck[i][13] = fmaf(hvf, wk3.y, acck[i][13]);
                acck[i][14] = fmaf(hvf, wk3.z, acck[i][14]);
                acck[i][15] = fmaf(hvf, wk3.w, acck[i][15]);
                accq[i][0]  = fmaf(hvf, wq0.x, accq[i][0]);
                accq[i][1]  = fmaf(hvf, wq0.y, accq[i][1]);
                accq[i][2]  = fmaf(hvf, wq0.z, accq[i][2]);
                accq[i][3]  = fmaf(hvf, wq0.w, accq[i][3]);
                accq[i][4]  = fmaf(hvf, wq1.x, accq[i][4]);
                accq[i][5]  = fmaf(hvf, wq1.y, accq[i][5]);
                accq[i][6]  = fmaf(hvf, wq1.z, accq[i][6]);
                accq[i][7]  = fmaf(hvf, wq1.w, accq[i][7]);
                accq[i][8]  = fmaf(hvf, wq2.x, accq[i][8]);
                accq[i][9]  = fmaf(hvf, wq2.y, accq[i][9]);
                accq[i][10] = fmaf(hvf, wq2.z, accq[i][10]);
                accq[i][11] = fmaf(hvf, wq2.w, accq[i][11]);
                accq[i][12] = fmaf(hvf, wq3.x, accq[i][12]);
                accq[i][13] = fmaf(hvf, wq3.y, accq[i][13]);
                accq[i][14] = fmaf(hvf, wq3.z, accq[i][14]);
                accq[i][15] = fmaf(hvf, wq3.w, accq[i][15]);
            }
        }
    }
#pragma unroll
    for (int i = 0; i < 2; ++i) {
        long r = base + i;
        if (r >= N) continue;
        float4* kout = (float4*)(k + (size_t)r * FDIM + cg * 16);
        float4* qout = (float4*)(q + (size_t)r * FDIM + cg * 16);
#pragma unroll
        for (int c4 = 0; c4 < 4; ++c4) {
            kout[c4] = make_float4(acck[i][c4*4], acck[i][c4*4+1], acck[i][c4*4+2], acck[i][c4*4+3]);
            qout[c4] = make_float4(accq[i][c4*4], accq[i][c4*4+1], accq[i][c4*4+2], accq[i][c4*4+3]);
        }
    }
}

// K2: histogram of in-degrees.
__global__ __launch_bounds__(256) void hist_kernel(
    const int* __restrict__ dst, int* __restrict__ counts, int E)
{
    int e = blockIdx.x * 256 + threadIdx.x;
    if (e < E) atomicAdd(&counts[dst[e]], 1);
}

// K3a: per-1024-chunk exclusive scan of counts -> rowptr, block totals -> bsum.
__global__ __launch_bounds__(256) void scan1_kernel(
    const int* __restrict__ counts, int* __restrict__ rowptr,
    int* __restrict__ bsum, int N)
{
    __shared__ int sd[256];
    int base = blockIdx.x * 1024;
    int t = threadIdx.x;
    int c[4];
    int s = 0;
#pragma unroll
    for (int i = 0; i < 4; ++i) {
        int idx = base + t * 4 + i;
        c[i] = (idx < N) ? counts[idx] : 0;
        s += c[i];
    }
    sd[t] = s;
    __syncthreads();
    for (int off = 1; off < 256; off <<= 1) {
        int v = (t >= off) ? sd[t - off] : 0;
        __syncthreads();
        sd[t] += v;
        __syncthreads();
    }
    int ex = sd[t] - s;
#pragma unroll
    for (int i = 0; i < 4; ++i) {
        int idx = base + t * 4 + i;
        if (idx < N) rowptr[idx] = ex;
        ex += c[i];
    }
    if (t == 255) bsum[blockIdx.x] = sd[255];
}

// K3b: single-block exclusive scan of bsum (NBLK <= 256).
__global__ __launch_bounds__(256) void scan2_kernel(int* __restrict__ bsum, int NBLK)
{
    __shared__ int sd[256];
    int t = threadIdx.x;
    int v = (t < NBLK) ? bsum[t] : 0;
    sd[t] = v;
    __syncthreads();
    for (int off = 1; off < 256; off <<= 1) {
        int u = (t >= off) ? sd[t - off] : 0;
        __syncthreads();
        sd[t] += u;
        __syncthreads();
    }
    if (t < NBLK) bsum[t] = sd[t] - v;
}

// K3c: add chunk offsets.
__global__ __launch_bounds__(256) void scan3_kernel(
    int* __restrict__ rowptr, const int* __restrict__ bsum, int N)
{
    int i = blockIdx.x * 256 + threadIdx.x;
    if (i < N) rowptr[i] += bsum[i >> 10];
}

// K4: fused score + scatter. Thread t = (edge, head). Lane group of 4 = one edge.
// Leader lane claims sorted slot p via atomicAdd (rowptr -> rowend), broadcasts p;
// each lane writes exp(<k[src],q[dst]>_head) into the 32B record; leader adds src.
// Record layout (8 floats): [ex0, ex1, ex2, ex3, bitcast(src), pad, pad, pad].
// No max-subtraction: |e| <~ 25 so exp stays far below fp32 overflow; a = ex/z is
// scale-invariant so result matches the reference to fp32 rounding.
__global__ __launch_bounds__(256) void score_scatter_kernel(
    const int* __restrict__ src, const int* __restrict__ dst,
    int* __restrict__ rowptr, const float* __restrict__ k,
    const float* __restrict__ q, float* __restrict__ recs, int E)
{
    int t = blockIdx.x * 256 + threadIdx.x;
    if (t >= E * NHEADS) return;
    int e  = t >> 2;
    int hh = t & 3;
    int s = src[e];
    int d = dst[e];
    int p = 0;
    if (hh == 0) p = atomicAdd(&rowptr[d], 1);
    p = __shfl(p, (threadIdx.x & 63) & ~3, 64);
    const float4* kr = (const float4*)(k + (size_t)s * FDIM + hh * 16);
    const float4* qr = (const float4*)(q + (size_t)d * FDIM + hh * 16);
    float acc = 0.f;
#pragma unroll
    for (int i = 0; i < 4; ++i) {
        float4 a  = kr[i];
        float4 bq = qr[i];
        acc += a.x * bq.x + a.y * bq.y + a.z * bq.z + a.w * bq.w;
    }
    float exv = expf(acc);
    recs[(size_t)p * 8 + hh] = exv;
    if (hh == 0) ((int*)recs)[(size_t)p * 8 + 4] = s;
}

// K5: gather aggregation over CSR rows of records. One wave per node; lane = feature.
// start/end from rowend (rowend[n-1], rowend[n]). Writes hn (= d_out) coalesced.
__global__ __launch_bounds__(256) void aggregate_kernel(
    const int* __restrict__ rowend, const float* __restrict__ recs,
    const float* __restrict__ h, float* __restrict__ hn, int N)
{
    int lane = threadIdx.x & 63;
    int n = blockIdx.x * 4 + (threadIdx.x >> 6);
    if (n >= N) return;
    int end   = rowend[n];
    int start = (n == 0) ? 0 : rowend[n - 1];
    const float4* recs4 = (const float4*)recs;
    const int*   recsi  = (const int*)recs;
    float a0 = 0.f, a1 = 0.f, a2 = 0.f, a3 = 0.f;
    float z0 = 0.f, z1 = 0.f, z2 = 0.f, z3 = 0.f;
    int i = start;
    for (; i + 1 < end; i += 2) {
        float4 e0 = recs4[(size_t)i * 2];
        float4 e1 = recs4[(size_t)(i + 1) * 2];
        int s0 = recsi[(size_t)i * 8 + 4];
        int s1 = recsi[(size_t)(i + 1) * 8 + 4];
        float hv0 = h[(size_t)s0 * FDIM + lane];
        float hv1 = h[(size_t)s1 * FDIM + lane];
        a0 = fmaf(e0.x, hv0, a0); a1 = fmaf(e0.y, hv0, a1);
        a2 = fmaf(e0.z, hv0, a2); a3 = fmaf(e0.w, hv0, a3);
        z0 += e0.x; z1 += e0.y; z2 += e0.z; z3 += e0.w;
        a0 = fmaf(e1.x, hv1, a0); a1 = fmaf(e1.y, hv1, a1);
        a2 = fmaf(e1.z, hv1, a2); a3 = fmaf(e1.w, hv1, a3);
        z0 += e1.x; z1 += e1.y; z2 += e1.z; z3 += e1.w;
    }
    if (i < end) {
        float4 e0 = recs4[(size_t)i * 2];
        int s0 = recsi[(size_t)i * 8 + 4];
        float hv0 = h[(size_t)s0 * FDIM + lane];
        a0 = fmaf(e0.x, hv0, a0); a1 = fmaf(e0.y, hv0, a1);
        a2 = fmaf(e0.z, hv0, a2); a3 = fmaf(e0.w, hv0, a3);
        z0 += e0.x; z1 += e0.y; z2 += e0.z; z3 += e0.w;
    }
    float* outr = hn + (size_t)n * (NHEADS * FDIM);
    if (end > start) {
        outr[lane]             = a0 / z0;
        outr[FDIM + lane]      = a1 / z1;
        outr[2 * FDIM + lane]  = a2 / z2;
        outr[3 * FDIM + lane]  = a3 / z3;
    } else {
        outr[lane] = 0.f;
        outr[FDIM + lane] = 0.f;
        outr[2 * FDIM + lane] = 0.f;
        outr[3 * FDIM + lane] = 0.f;
    }
}

// K6: out = hn @ W + b, IN PLACE (hn == out == d_out). Thread = 4 rows x 16 cols.
// Safe in place: the 4 threads (cg=0..3) sharing a row-group are consecutive lanes
// of one wave, so in lockstep all their row reads complete before any store.
// No __restrict__ on hn/out (they alias).
__global__ __launch_bounds__(256) void out_kernel(
    const float* hn, const float* __restrict__ W,
    const float* __restrict__ b, float* out, int R)
{
    __shared__ float sW[FDIM * FDIM];
    __shared__ float sb[FDIM];
    for (int i = threadIdx.x; i < FDIM * FDIM; i += 256) sW[i] = W[i];
    if (threadIdx.x < FDIM) sb[threadIdx.x] = b[threadIdx.x];
    __syncthreads();
    int cg = threadIdx.x & 3;
    int rg = threadIdx.x >> 2;
    long base = (long)blockIdx.x * 256 + rg * 4;
    const float4* sW4 = (const float4*)sW;
    const float4* hn4 = (const float4*)hn;
    float acc[4][16];
#pragma unroll
    for (int i = 0; i < 4; ++i)
#pragma unroll
        for (int c = 0; c < 16; ++c) acc[i][c] = sb[cg * 16 + c];

    for (int fs = 0; fs < FDIM; fs += 4) {
        float4 hv[4];
#pragma unroll
        for (int i = 0; i < 4; ++i) {
            long r = base + i; if (r >= R) r = R - 1;
            hv[i] = hn4[r * 16 + (fs >> 2)];
        }
#pragma unroll
        for (int fi = 0; fi < 4; ++fi) {
            int f = fs + fi;
            float4 w0 = sW4[f * 16 + cg * 4 + 0];
            float4 w1 = sW4[f * 16 + cg * 4 + 1];
            float4 w2 = sW4[f * 16 + cg * 4 + 2];
            float4 w3 = sW4[f * 16 + cg * 4 + 3];
#pragma unroll
            for (int i = 0; i < 4; ++i) {
                float hvf = (&hv[i].x)[fi];
                acc[i][0]  = fmaf(hvf, w0.x, acc[i][0]);
                acc[i][1]  = fmaf(hvf, w0.y, acc[i][1]);
                acc[i][2]  = fmaf(hvf, w0.z, acc[i][2]);
                acc[i][3]  = fmaf(hvf, w0.w, acc[i][3]);
                acc[i][4]  = fmaf(hvf, w1.x, acc[i][4]);
                acc[i][5]  = fmaf(hvf, w1.y, acc[i][5]);
                acc[i][6]  = fmaf(hvf, w1.z, acc[i][6]);
                acc[i][7]  = fmaf(hvf, w1.w, acc[i][7]);
                acc[i][8]  = fmaf(hvf, w2.x, acc[i][8]);
                acc[i][9]  = fmaf(hvf, w2.y, acc[i][9]);
                acc[i][10] = fmaf(hvf, w2.z, acc[i][10]);
                acc[i][11] = fmaf(hvf, w2.w, acc[i][11]);
                acc[i][12] = fmaf(hvf, w3.x, acc[i][12]);
                acc[i][13] = fmaf(hvf, w3.y, acc[i][13]);
                acc[i][14] = fmaf(hvf, w3.z, acc[i][14]);
                acc[i][15] = fmaf(hvf, w3.w, acc[i][15]);
            }
        }
    }
#pragma unroll
    for (int i = 0; i < 4; ++i) {
        long r = base + i;
        if (r >= R) continue;
        float4* o = (float4*)(out + (size_t)r * FDIM + cg * 16);
#pragma unroll
        for (int c4 = 0; c4 < 4; ++c4)
            o[c4] = make_float4(acc[i][c4*4], acc[i][c4*4+1], acc[i][c4*4+2], acc[i][c4*4+3]);
    }
}

extern "C" void kernel_launch(void* const* d_in, const int* in_sizes, int n_in,
                              void* d_out, int out_size, void* d_ws, size_t ws_size,
                              hipStream_t stream) {
    const float* h   = (const float*)d_in[0];
    const int*   src = (const int*)d_in[1];
    const int*   dst = (const int*)d_in[2];
    const float* Wk  = (const float*)d_in[3];
    const float* Wq  = (const float*)d_in[4];
    const float* W   = (const float*)d_in[5];
    const float* b   = (const float*)d_in[6];
    float* out = (float*)d_out;

    const int N = in_sizes[0] / FDIM;   // 100000
    const int E = in_sizes[1];          // 1600000

    // Workspace (floats): k[N*64] q[N*64] recs[E*8] | counts[N] rowptr[N] bsum[256]
    // hn lives in d_out (aggregate writes it; out GEMM runs in place).
    float* ws = (float*)d_ws;
    float* k    = ws;
    float* q    = k + (size_t)N * FDIM;
    float* recs = q + (size_t)N * FDIM;
    int* counts = (int*)(recs + (size_t)E * 8);
    int* rowptr = counts + N;
    int* bsum   = rowptr + N;

    const int NBLK = (N + 1023) / 1024;  // 98

    hipMemsetAsync(counts, 0, (size_t)N * sizeof(int), stream);

    kq_kernel<<<(N + 127) / 128, 256, 0, stream>>>(h, Wk, Wq, k, q, N);
    hist_kernel<<<(E + 255) / 256, 256, 0, stream>>>(dst, counts, E);
    scan1_kernel<<<NBLK, 256, 0, stream>>>(counts, rowptr, bsum, N);
    scan2_kernel<<<1, 256, 0, stream>>>(bsum, NBLK);
    scan3_kernel<<<(N + 255) / 256, 256, 0, stream>>>(rowptr, bsum, N);
    score_scatter_kernel<<<(E * NHEADS + 255) / 256, 256, 0, stream>>>(
        src, dst, rowptr, k, q, recs, E);
    aggregate_kernel<<<(N + 3) / 4, 256, 0, stream>>>(rowptr, recs, h, out, N);
    out_kernel<<<(N * NHEADS + 255) / 256, 256, 0, stream>>>(out, W, b, out, N * NHEADS);
}

// Round 5
// 531.601 us; speedup vs baseline: 3.5299x; 1.1004x over previous
//
#include <hip/hip_runtime.h>
#include <hip/hip_fp16.h>
#include <math.h>

// GAT layer: N=100000, E=1600000, F=64, H=4 (Dh=16).
// Pipeline: kq GEMM (fp32 acc -> fp16 store) -> h->fp16 -> hist -> scan ->
// fused score+scatter (fp16 gathers, 32B sorted records {ex0..3 fp32, src}) ->
// CSR gather-aggregate (fp16 h, writes d_out) -> in-place output GEMM.

#define FDIM 64
#define NHEADS 4

// K1: k = h @ Wk, q = h @ Wq. Thread = 2 rows x 16 cols x 2 matrices.
// fp32 accumulate, fp16 store (score only needs ~3 digits; halves gather bytes).
__global__ __launch_bounds__(256) void kq_kernel(
    const float* __restrict__ h, const float* __restrict__ Wk,
    const float* __restrict__ Wq, __half* __restrict__ k16,
    __half* __restrict__ q16, int N)
{
    __shared__ float sWk[FDIM * FDIM];
    __shared__ float sWq[FDIM * FDIM];
    for (int i = threadIdx.x; i < FDIM * FDIM; i += 256) {
        sWk[i] = Wk[i];
        sWq[i] = Wq[i];
    }
    __syncthreads();
    int cg = threadIdx.x & 3;
    int rg = threadIdx.x >> 2;
    long base = (long)blockIdx.x * 128 + rg * 2;
    const float4* sWk4 = (const float4*)sWk;
    const float4* sWq4 = (const float4*)sWq;
    const float4* h4 = (const float4*)h;
    float acck[2][16], accq[2][16];
#pragma unroll
    for (int i = 0; i < 2; ++i)
#pragma unroll
        for (int c = 0; c < 16; ++c) { acck[i][c] = 0.f; accq[i][c] = 0.f; }

    for (int fs = 0; fs < FDIM; fs += 4) {
        float4 hv[2];
#pragma unroll
        for (int i = 0; i < 2; ++i) {
            long r = base + i; if (r >= N) r = N - 1;
            hv[i] = h4[r * 16 + (fs >> 2)];
        }
#pragma unroll
        for (int fi = 0; fi < 4; ++fi) {
            int f = fs + fi;
            float4 wk0 = sWk4[f * 16 + cg * 4 + 0];
            float4 wk1 = sWk4[f * 16 + cg * 4 + 1];
            float4 wk2 = sWk4[f * 16 + cg * 4 + 2];
            float4 wk3 = sWk4[f * 16 + cg * 4 + 3];
            float4 wq0 = sWq4[f * 16 + cg * 4 + 0];
            float4 wq1 = sWq4[f * 16 + cg * 4 + 1];
            float4 wq2 = sWq4[f * 16 + cg * 4 + 2];
            float4 wq3 = sWq4[f * 16 + cg * 4 + 3];
#pragma unroll
            for (int i = 0; i < 2; ++i) {
                float hvf = (&hv[i].x)[fi];
                acck[i][0]  = fmaf(hvf, wk0.x, acck[i][0]);
                acck[i][1]  = fmaf(hvf, wk0.y, acck[i][1]);
                acck[i][2]  = fmaf(hvf, wk0.z, acck[i][2]);
                acck[i][3]  = fmaf(hvf, wk0.w, acck[i][3]);
                acck[i][4]  = fmaf(hvf, wk1.x, acck[i][4]);
                acck[i][5]  = fmaf(hvf, wk1.y, acck[i][5]);
                acck[i][6]  = fmaf(hvf, wk1.z, acck[i][6]);
                acck[i][7]  = fmaf(hvf, wk1.w, acck[i][7]);
                acck[i][8]  = fmaf(hvf, wk2.x, acck[i][8]);
                acck[i][9]  = fmaf(hvf, wk2.y, acck[i][9]);
                acck[i][10] = fmaf(hvf, wk2.z, acck[i][10]);
                acck[i][11] = fmaf(hvf, wk2.w, acck[i][11]);
                acck[i][12] = fmaf(hvf, wk3.x, acck[i][12]);
                acck[i][13] = fmaf(hvf, wk3.y, acck[i][13]);
                acck[i][14] = fmaf(hvf, wk3.z, acck[i][14]);
                acck[i][15] = fmaf(hvf, wk3.w, acck[i][15]);
                accq[i][0]  = fmaf(hvf, wq0.x, accq[i][0]);
                accq[i][1]  = fmaf(hvf, wq0.y, accq[i][1]);
                accq[i][2]  = fmaf(hvf, wq0.z, accq[i][2]);
                accq[i][3]  = fmaf(hvf, wq0.w, accq[i][3]);
                accq[i][4]  = fmaf(hvf, wq1.x, accq[i][4]);
                accq[i][5]  = fmaf(hvf, wq1.y, accq[i][5]);
                accq[i][6]  = fmaf(hvf, wq1.z, accq[i][6]);
                accq[i][7]  = fmaf(hvf, wq1.w, accq[i][7]);
                accq[i][8]  = fmaf(hvf, wq2.x, accq[i][8]);
                accq[i][9]  = fmaf(hvf, wq2.y, accq[i][9]);
                accq[i][10] = fmaf(hvf, wq2.z, accq[i][10]);
                accq[i][11] = fmaf(hvf, wq2.w, accq[i][11]);
                accq[i][12] = fmaf(hvf, wq3.x, accq[i][12]);
                accq[i][13] = fmaf(hvf, wq3.y, accq[i][13]);
                accq[i][14] = fmaf(hvf, wq3.z, accq[i][14]);
                accq[i][15] = fmaf(hvf, wq3.w, accq[i][15]);
            }
        }
    }
#pragma unroll
    for (int i = 0; i < 2; ++i) {
        long r = base + i;
        if (r >= N) continue;
        __half2 hk[8], hq[8];
#pragma unroll
        for (int c = 0; c < 8; ++c) {
            hk[c] = __floats2half2_rn(acck[i][2 * c], acck[i][2 * c + 1]);
            hq[c] = __floats2half2_rn(accq[i][2 * c], accq[i][2 * c + 1]);
        }
        float4* kout = (float4*)(k16 + (size_t)r * FDIM + cg * 16);
        float4* qout = (float4*)(q16 + (size_t)r * FDIM + cg * 16);
        kout[0] = ((float4*)hk)[0]; kout[1] = ((float4*)hk)[1];
        qout[0] = ((float4*)hq)[0]; qout[1] = ((float4*)hq)[1];
    }
}

// K1b: h -> fp16 copy for the aggregate gather. 8 elems/thread. total % 8 == 0.
__global__ __launch_bounds__(256) void h2half_kernel(
    const float* __restrict__ h, __half* __restrict__ h16, int total)
{
    int i = blockIdx.x * 256 + threadIdx.x;
    size_t base = (size_t)i * 8;
    if (base >= (size_t)total) return;
    const float4* h4 = (const float4*)(h + base);
    float4 a = h4[0], b = h4[1];
    __half2 o[4] = { __floats2half2_rn(a.x, a.y), __floats2half2_rn(a.z, a.w),
                     __floats2half2_rn(b.x, b.y), __floats2half2_rn(b.z, b.w) };
    *(float4*)(h16 + base) = *(float4*)o;
}

// K2: histogram of in-degrees.
__global__ __launch_bounds__(256) void hist_kernel(
    const int* __restrict__ dst, int* __restrict__ counts, int E)
{
    int e = blockIdx.x * 256 + threadIdx.x;
    if (e < E) atomicAdd(&counts[dst[e]], 1);
}

// K3a: per-1024-chunk exclusive scan of counts -> rowptr, block totals -> bsum.
__global__ __launch_bounds__(256) void scan1_kernel(
    const int* __restrict__ counts, int* __restrict__ rowptr,
    int* __restrict__ bsum, int N)
{
    __shared__ int sd[256];
    int base = blockIdx.x * 1024;
    int t = threadIdx.x;
    int c[4];
    int s = 0;
#pragma unroll
    for (int i = 0; i < 4; ++i) {
        int idx = base + t * 4 + i;
        c[i] = (idx < N) ? counts[idx] : 0;
        s += c[i];
    }
    sd[t] = s;
    __syncthreads();
    for (int off = 1; off < 256; off <<= 1) {
        int v = (t >= off) ? sd[t - off] : 0;
        __syncthreads();
        sd[t] += v;
        __syncthreads();
    }
    int ex = sd[t] - s;
#pragma unroll
    for (int i = 0; i < 4; ++i) {
        int idx = base + t * 4 + i;
        if (idx < N) rowptr[idx] = ex;
        ex += c[i];
    }
    if (t == 255) bsum[blockIdx.x] = sd[255];
}

// K3b: single-block exclusive scan of bsum (NBLK <= 256).
__global__ __launch_bounds__(256) void scan2_kernel(int* __restrict__ bsum, int NBLK)
{
    __shared__ int sd[256];
    int t = threadIdx.x;
    int v = (t < NBLK) ? bsum[t] : 0;
    sd[t] = v;
    __syncthreads();
    for (int off = 1; off < 256; off <<= 1) {
        int u = (t >= off) ? sd[t - off] : 0;
        __syncthreads();
        sd[t] += u;
        __syncthreads();
    }
    if (t < NBLK) bsum[t] = sd[t] - v;
}

// K3c: add chunk offsets.
__global__ __launch_bounds__(256) void scan3_kernel(
    int* __restrict__ rowptr, const int* __restrict__ bsum, int N)
{
    int i = blockIdx.x * 256 + threadIdx.x;
    if (i < N) rowptr[i] += bsum[i >> 10];
}

// K4: fused score + scatter, fp16 k/q gathers. Thread t = (edge, head); 4-lane
// group = one edge. Leader claims sorted slot p (rowptr -> rowend), broadcasts.
// Record (8 floats): [ex0..ex3 (fp32 - huge dynamic range, no max-sub), src, pad x3].
__global__ __launch_bounds__(256) void score_scatter_kernel(
    const int* __restrict__ src, const int* __restrict__ dst,
    int* __restrict__ rowptr, const __half* __restrict__ k16,
    const __half* __restrict__ q16, float* __restrict__ recs, int E)
{
    int t = blockIdx.x * 256 + threadIdx.x;
    if (t >= E * NHEADS) return;
    int e  = t >> 2;
    int hh = t & 3;
    int s = src[e];
    int d = dst[e];
    int p = 0;
    if (hh == 0) p = atomicAdd(&rowptr[d], 1);
    p = __shfl(p, (threadIdx.x & 63) & ~3, 64);
    const float4* kr = (const float4*)(k16 + (size_t)s * FDIM + hh * 16);
    const float4* qr = (const float4*)(q16 + (size_t)d * FDIM + hh * 16);
    float4 kv[2], qv[2];
    kv[0] = kr[0]; kv[1] = kr[1];
    qv[0] = qr[0]; qv[1] = qr[1];
    const __half2* kh = (const __half2*)kv;
    const __half2* qh = (const __half2*)qv;
    float acc = 0.f;
#pragma unroll
    for (int j = 0; j < 8; ++j) {
        float2 kf = __half22float2(kh[j]);
        float2 qf = __half22float2(qh[j]);
        acc = fmaf(kf.x, qf.x, acc);
        acc = fmaf(kf.y, qf.y, acc);
    }
    float exv = expf(acc);
    recs[(size_t)p * 8 + hh] = exv;
    if (hh == 0) ((int*)recs)[(size_t)p * 8 + 4] = s;
}

// K5: gather aggregation over CSR rows. One wave per node; lane = feature.
// fp16 h gather (2B/lane, coalesced 128B/wave). Writes hn (= d_out).
__global__ __launch_bounds__(256) void aggregate_kernel(
    const int* __restrict__ rowend, const float* __restrict__ recs,
    const __half* __restrict__ h16, float* __restrict__ hn, int N)
{
    int lane = threadIdx.x & 63;
    int n = blockIdx.x * 4 + (threadIdx.x >> 6);
    if (n >= N) return;
    int end   = rowend[n];
    int start = (n == 0) ? 0 : rowend[n - 1];
    const float4* recs4 = (const float4*)recs;
    const int*   recsi  = (const int*)recs;
    float a0 = 0.f, a1 = 0.f, a2 = 0.f, a3 = 0.f;
    float z0 = 0.f, z1 = 0.f, z2 = 0.f, z3 = 0.f;
    int i = start;
    for (; i + 1 < end; i += 2) {
        float4 e0 = recs4[(size_t)i * 2];
        float4 e1 = recs4[(size_t)(i + 1) * 2];
        int s0 = recsi[(size_t)i * 8 + 4];
        int s1 = recsi[(size_t)(i + 1) * 8 + 4];
        float hv0 = __half2float(h16[(size_t)s0 * FDIM + lane]);
        float hv1 = __half2float(h16[(size_t)s1 * FDIM + lane]);
        a0 = fmaf(e0.x, hv0, a0); a1 = fmaf(e0.y, hv0, a1);
        a2 = fmaf(e0.z, hv0, a2); a3 = fmaf(e0.w, hv0, a3);
        z0 += e0.x; z1 += e0.y; z2 += e0.z; z3 += e0.w;
        a0 = fmaf(e1.x, hv1, a0); a1 = fmaf(e1.y, hv1, a1);
        a2 = fmaf(e1.z, hv1, a2); a3 = fmaf(e1.w, hv1, a3);
        z0 += e1.x; z1 += e1.y; z2 += e1.z; z3 += e1.w;
    }
    if (i < end) {
        float4 e0 = recs4[(size_t)i * 2];
        int s0 = recsi[(size_t)i * 8 + 4];
        float hv0 = __half2float(h16[(size_t)s0 * FDIM + lane]);
        a0 = fmaf(e0.x, hv0, a0); a1 = fmaf(e0.y, hv0, a1);
        a2 = fmaf(e0.z, hv0, a2); a3 = fmaf(e0.w, hv0, a3);
        z0 += e0.x; z1 += e0.y; z2 += e0.z; z3 += e0.w;
    }
    float* outr = hn + (size_t)n * (NHEADS * FDIM);
    if (end > start) {
        outr[lane]             = a0 / z0;
        outr[FDIM + lane]      = a1 / z1;
        outr[2 * FDIM + lane]  = a2 / z2;
        outr[3 * FDIM + lane]  = a3 / z3;
    } else {
        outr[lane] = 0.f;
        outr[FDIM + lane] = 0.f;
        outr[2 * FDIM + lane] = 0.f;
        outr[3 * FDIM + lane] = 0.f;
    }
}

// K6: out = hn @ W + b, IN PLACE (hn == out == d_out). Thread = 4 rows x 16 cols.
// In-place safe: the 4 threads sharing a row-group are consecutive lanes of one
// wave, so all row reads complete before any store (lockstep).
__global__ __launch_bounds__(256) void out_kernel(
    const float* hn, const float* __restrict__ W,
    const float* __restrict__ b, float* out, int R)
{
    __shared__ float sW[FDIM * FDIM];
    __shared__ float sb[FDIM];
    for (int i = threadIdx.x; i < FDIM * FDIM; i += 256) sW[i] = W[i];
    if (threadIdx.x < FDIM) sb[threadIdx.x] = b[threadIdx.x];
    __syncthreads();
    int cg = threadIdx.x & 3;
    int rg = threadIdx.x >> 2;
    long base = (long)blockIdx.x * 256 + rg * 4;
    const float4* sW4 = (const float4*)sW;
    const float4* hn4 = (const float4*)hn;
    float acc[4][16];
#pragma unroll
    for (int i = 0; i < 4; ++i)
#pragma unroll
        for (int c = 0; c < 16; ++c) acc[i][c] = sb[cg * 16 + c];

    for (int fs = 0; fs < FDIM; fs += 4) {
        float4 hv[4];
#pragma unroll
        for (int i = 0; i < 4; ++i) {
            long r = base + i; if (r >= R) r = R - 1;
            hv[i] = hn4[r * 16 + (fs >> 2)];
        }
#pragma unroll
        for (int fi = 0; fi < 4; ++fi) {
            int f = fs + fi;
            float4 w0 = sW4[f * 16 + cg * 4 + 0];
            float4 w1 = sW4[f * 16 + cg * 4 + 1];
            float4 w2 = sW4[f * 16 + cg * 4 + 2];
            float4 w3 = sW4[f * 16 + cg * 4 + 3];
#pragma unroll
            for (int i = 0; i < 4; ++i) {
                float hvf = (&hv[i].x)[fi];
                acc[i][0]  = fmaf(hvf, w0.x, acc[i][0]);
                acc[i][1]  = fmaf(hvf, w0.y, acc[i][1]);
                acc[i][2]  = fmaf(hvf, w0.z, acc[i][2]);
                acc[i][3]  = fmaf(hvf, w0.w, acc[i][3]);
                acc[i][4]  = fmaf(hvf, w1.x, acc[i][4]);
                acc[i][5]  = fmaf(hvf, w1.y, acc[i][5]);
                acc[i][6]  = fmaf(hvf, w1.z, acc[i][6]);
                acc[i][7]  = fmaf(hvf, w1.w, acc[i][7]);
                acc[i][8]  = fmaf(hvf, w2.x, acc[i][8]);
                acc[i][9]  = fmaf(hvf, w2.y, acc[i][9]);
                acc[i][10] = fmaf(hvf, w2.z, acc[i][10]);
                acc[i][11] = fmaf(hvf, w2.w, acc[i][11]);
                acc[i][12] = fmaf(hvf, w3.x, acc[i][12]);
                acc[i][13] = fmaf(hvf, w3.y, acc[i][13]);
                acc[i][14] = fmaf(hvf, w3.z, acc[i][14]);
                acc[i][15] = fmaf(hvf, w3.w, acc[i][15]);
            }
        }
    }
#pragma unroll
    for (int i = 0; i < 4; ++i) {
        long r = base + i;
        if (r >= R) continue;
        float4* o = (float4*)(out + (size_t)r * FDIM + cg * 16);
#pragma unroll
        for (int c4 = 0; c4 < 4; ++c4)
            o[c4] = make_float4(acc[i][c4*4], acc[i][c4*4+1], acc[i][c4*4+2], acc[i][c4*4+3]);
    }
}

extern "C" void kernel_launch(void* const* d_in, const int* in_sizes, int n_in,
                              void* d_out, int out_size, void* d_ws, size_t ws_size,
                              hipStream_t stream) {
    const float* h   = (const float*)d_in[0];
    const int*   src = (const int*)d_in[1];
    const int*   dst = (const int*)d_in[2];
    const float* Wk  = (const float*)d_in[3];
    const float* Wq  = (const float*)d_in[4];
    const float* W   = (const float*)d_in[5];
    const float* b   = (const float*)d_in[6];
    float* out = (float*)d_out;

    const int N = in_sizes[0] / FDIM;   // 100000
    const int E = in_sizes[1];          // 1600000

    // Workspace: k16[N*64 h], q16[N*64 h], h16[N*64 h], recs[E*8 f],
    //            counts[N], rowptr[N], bsum[256].  (~91 MB)
    __half* k16 = (__half*)d_ws;
    __half* q16 = k16 + (size_t)N * FDIM;
    __half* h16 = q16 + (size_t)N * FDIM;
    float* recs = (float*)(h16 + (size_t)N * FDIM);
    int* counts = (int*)(recs + (size_t)E * 8);
    int* rowptr = counts + N;
    int* bsum   = rowptr + N;

    const int NBLK = (N + 1023) / 1024;  // 98
    const int HT = N * FDIM;             // 6.4M, % 8 == 0

    hipMemsetAsync(counts, 0, (size_t)N * sizeof(int), stream);

    kq_kernel<<<(N + 127) / 128, 256, 0, stream>>>(h, Wk, Wq, k16, q16, N);
    h2half_kernel<<<(HT / 8 + 255) / 256, 256, 0, stream>>>(h, h16, HT);
    hist_kernel<<<(E + 255) / 256, 256, 0, stream>>>(dst, counts, E);
    scan1_kernel<<<NBLK, 256, 0, stream>>>(counts, rowptr, bsum, N);
    scan2_kernel<<<1, 256, 0, stream>>>(bsum, NBLK);
    scan3_kernel<<<(N + 255) / 256, 256, 0, stream>>>(rowptr, bsum, N);
    score_scatter_kernel<<<(E * NHEADS + 255) / 256, 256, 0, stream>>>(
        src, dst, rowptr, k16, q16, recs, E);
    aggregate_kernel<<<(N + 3) / 4, 256, 0, stream>>>(rowptr, recs, h16, out, N);
    out_kernel<<<(N * NHEADS + 255) / 256, 256, 0, stream>>>(out, W, b, out, N * NHEADS);
}

// Round 7
// 501.643 us; speedup vs baseline: 3.7407x; 1.0597x over previous
//
#include <hip/hip_runtime.h>
#include <hip/hip_fp16.h>
#include <math.h>

// GAT layer: N=100000, E=1600000, F=64, H=4 (Dh=16).
// Pipeline: fused {kq GEMM (fp16 out) | h->fp16 | in-degree hist} -> scan ->
// fused score+scatter (fp16 gathers, 16B sqrt-domain records, leader uint4
// store) -> CSR gather-aggregate (fp16 h, writes d_out) -> in-place out GEMM.
//
// Record (16B): { half2(r0,r1), half2(r2,r3), f32 exp(m), src } where
// r_h = exp((e_h - m)/2), m = max_h e_h (per edge). Weight_h = r_h^2 * exp(m)
// = exp(e_h) exactly. Sqrt domain doubles fp16 underflow margin: flush needs
// cross-head spread > 34 (~6 sigma of the N(0,32) head-diff) vs 17 for the
// linear domain, which measurably corrupted dominant edges (R5 absmax 1.71).

#define FDIM 64
#define NHEADS 4

// ---- K1: multi-role kernel: [0,KQB) kq | [KQB,KQB+H2B) h2half | rest hist ----
__global__ __launch_bounds__(256) void fused_pre_kernel(
    const float* __restrict__ h, const float* __restrict__ Wk,
    const float* __restrict__ Wq, __half* __restrict__ k16,
    __half* __restrict__ q16, __half* __restrict__ h16,
    const int* __restrict__ dst, int* __restrict__ counts,
    int N, int E, int KQB, int H2B)
{
    __shared__ float sWk[FDIM * FDIM];
    __shared__ float sWq[FDIM * FDIM];
    int bid = blockIdx.x;
    if (bid < KQB) {
        // --- kq role: k = h@Wk, q = h@Wq; thread = 2 rows x 16 cols x 2 mats ---
        for (int i = threadIdx.x; i < FDIM * FDIM; i += 256) {
            sWk[i] = Wk[i];
            sWq[i] = Wq[i];
        }
        __syncthreads();
        int cg = threadIdx.x & 3;
        int rg = threadIdx.x >> 2;
        long base = (long)bid * 128 + rg * 2;
        const float4* sWk4 = (const float4*)sWk;
        const float4* sWq4 = (const float4*)sWq;
        const float4* h4 = (const float4*)h;
        float acck[2][16], accq[2][16];
#pragma unroll
        for (int i = 0; i < 2; ++i)
#pragma unroll
            for (int c = 0; c < 16; ++c) { acck[i][c] = 0.f; accq[i][c] = 0.f; }

        for (int fs = 0; fs < FDIM; fs += 4) {
            float4 hv[2];
#pragma unroll
            for (int i = 0; i < 2; ++i) {
                long r = base + i; if (r >= N) r = N - 1;
                hv[i] = h4[r * 16 + (fs >> 2)];
            }
#pragma unroll
            for (int fi = 0; fi < 4; ++fi) {
                int f = fs + fi;
                float4 wk0 = sWk4[f * 16 + cg * 4 + 0];
                float4 wk1 = sWk4[f * 16 + cg * 4 + 1];
                float4 wk2 = sWk4[f * 16 + cg * 4 + 2];
                float4 wk3 = sWk4[f * 16 + cg * 4 + 3];
                float4 wq0 = sWq4[f * 16 + cg * 4 + 0];
                float4 wq1 = sWq4[f * 16 + cg * 4 + 1];
                float4 wq2 = sWq4[f * 16 + cg * 4 + 2];
                float4 wq3 = sWq4[f * 16 + cg * 4 + 3];
#pragma unroll
                for (int i = 0; i < 2; ++i) {
                    float hvf = (&hv[i].x)[fi];
                    acck[i][0]  = fmaf(hvf, wk0.x, acck[i][0]);
                    acck[i][1]  = fmaf(hvf, wk0.y, acck[i][1]);
                    acck[i][2]  = fmaf(hvf, wk0.z, acck[i][2]);
                    acck[i][3]  = fmaf(hvf, wk0.w, acck[i][3]);
                    acck[i][4]  = fmaf(hvf, wk1.x, acck[i][4]);
                    acck[i][5]  = fmaf(hvf, wk1.y, acck[i][5]);
                    acck[i][6]  = fmaf(hvf, wk1.z, acck[i][6]);
                    acck[i][7]  = fmaf(hvf, wk1.w, acck[i][7]);
                    acck[i][8]  = fmaf(hvf, wk2.x, acck[i][8]);
                    acck[i][9]  = fmaf(hvf, wk2.y, acck[i][9]);
                    acck[i][10] = fmaf(hvf, wk2.z, acck[i][10]);
                    acck[i][11] = fmaf(hvf, wk2.w, acck[i][11]);
                    acck[i][12] = fmaf(hvf, wk3.x, acck[i][12]);
                    acck[i][13] = fmaf(hvf, wk3.y, acck[i][13]);
                    acck[i][14] = fmaf(hvf, wk3.z, acck[i][14]);
                    acck[i][15] = fmaf(hvf, wk3.w, acck[i][15]);
                    accq[i][0]  = fmaf(hvf, wq0.x, accq[i][0]);
                    accq[i][1]  = fmaf(hvf, wq0.y, accq[i][1]);
                    accq[i][2]  = fmaf(hvf, wq0.z, accq[i][2]);
                    accq[i][3]  = fmaf(hvf, wq0.w, accq[i][3]);
                    accq[i][4]  = fmaf(hvf, wq1.x, accq[i][4]);
                    accq[i][5]  = fmaf(hvf, wq1.y, accq[i][5]);
                    accq[i][6]  = fmaf(hvf, wq1.z, accq[i][6]);
                    accq[i][7]  = fmaf(hvf, wq1.w, accq[i][7]);
                    accq[i][8]  = fmaf(hvf, wq2.x, accq[i][8]);
                    accq[i][9]  = fmaf(hvf, wq2.y, accq[i][9]);
                    accq[i][10] = fmaf(hvf, wq2.z, accq[i][10]);
                    accq[i][11] = fmaf(hvf, wq2.w, accq[i][11]);
                    accq[i][12] = fmaf(hvf, wq3.x, accq[i][12]);
                    accq[i][13] = fmaf(hvf, wq3.y, accq[i][13]);
                    accq[i][14] = fmaf(hvf, wq3.z, accq[i][14]);
                    accq[i][15] = fmaf(hvf, wq3.w, accq[i][15]);
                }
            }
        }
#pragma unroll
        for (int i = 0; i < 2; ++i) {
            long r = base + i;
            if (r >= N) continue;
            __half2 hk[8], hq[8];
#pragma unroll
            for (int c = 0; c < 8; ++c) {
                hk[c] = __floats2half2_rn(acck[i][2 * c], acck[i][2 * c + 1]);
                hq[c] = __floats2half2_rn(accq[i][2 * c], accq[i][2 * c + 1]);
            }
            float4* kout = (float4*)(k16 + (size_t)r * FDIM + cg * 16);
            float4* qout = (float4*)(q16 + (size_t)r * FDIM + cg * 16);
            kout[0] = ((float4*)hk)[0]; kout[1] = ((float4*)hk)[1];
            qout[0] = ((float4*)hq)[0]; qout[1] = ((float4*)hq)[1];
        }
    } else if (bid < KQB + H2B) {
        // --- h2half role: h -> fp16, 8 elems/thread ---
        int i = (bid - KQB) * 256 + threadIdx.x;
        size_t base = (size_t)i * 8;
        size_t total = (size_t)N * FDIM;
        if (base >= total) return;
        const float4* h4 = (const float4*)(h + base);
        float4 a = h4[0], b2 = h4[1];
        __half2 o[4] = { __floats2half2_rn(a.x, a.y), __floats2half2_rn(a.z, a.w),
                         __floats2half2_rn(b2.x, b2.y), __floats2half2_rn(b2.z, b2.w) };
        *(float4*)(h16 + base) = *(float4*)o;
    } else {
        // --- hist role: in-degree histogram ---
        int e = (bid - KQB - H2B) * 256 + threadIdx.x;
        if (e < E) atomicAdd(&counts[dst[e]], 1);
    }
}

// K2a: per-1024-chunk exclusive scan of counts -> rowptr, block totals -> bsum.
__global__ __launch_bounds__(256) void scan1_kernel(
    const int* __restrict__ counts, int* __restrict__ rowptr,
    int* __restrict__ bsum, int N)
{
    __shared__ int sd[256];
    int base = blockIdx.x * 1024;
    int t = threadIdx.x;
    int c[4];
    int s = 0;
#pragma unroll
    for (int i = 0; i < 4; ++i) {
        int idx = base + t * 4 + i;
        c[i] = (idx < N) ? counts[idx] : 0;
        s += c[i];
    }
    sd[t] = s;
    __syncthreads();
    for (int off = 1; off < 256; off <<= 1) {
        int v = (t >= off) ? sd[t - off] : 0;
        __syncthreads();
        sd[t] += v;
        __syncthreads();
    }
    int ex = sd[t] - s;
#pragma unroll
    for (int i = 0; i < 4; ++i) {
        int idx = base + t * 4 + i;
        if (idx < N) rowptr[idx] = ex;
        ex += c[i];
    }
    if (t == 255) bsum[blockIdx.x] = sd[255];
}

// K2b: single-block exclusive scan of bsum (NBLK <= 256).
__global__ __launch_bounds__(256) void scan2_kernel(int* __restrict__ bsum, int NBLK)
{
    __shared__ int sd[256];
    int t = threadIdx.x;
    int v = (t < NBLK) ? bsum[t] : 0;
    sd[t] = v;
    __syncthreads();
    for (int off = 1; off < 256; off <<= 1) {
        int u = (t >= off) ? sd[t - off] : 0;
        __syncthreads();
        sd[t] += u;
        __syncthreads();
    }
    if (t < NBLK) bsum[t] = sd[t] - v;
}

// K2c: add chunk offsets.
__global__ __launch_bounds__(256) void scan3_kernel(
    int* __restrict__ rowptr, const int* __restrict__ bsum, int N)
{
    int i = blockIdx.x * 256 + threadIdx.x;
    if (i < N) rowptr[i] += bsum[i >> 10];
}

// K3: fused score + scatter, 2 edges/thread. 4-lane group = one edge (lane hh
// = head). Per edge: gather fp16 k[src]/q[dst], dot over 16 dims, group-max via
// shfl_xor, r_h = exp((e_h - m)/2) packed fp16, leader stores ONE 16B record.
__global__ __launch_bounds__(256) void score_scatter_kernel(
    const int* __restrict__ src, const int* __restrict__ dst,
    int* __restrict__ rowptr, const __half* __restrict__ k16,
    const __half* __restrict__ q16, uint4* __restrict__ recs, int E)
{
    int t = blockIdx.x * 256 + threadIdx.x;
    int hh = t & 3;
    int Ehalf = (E + 1) >> 1;
    int eA = t >> 2;
    if (eA >= Ehalf) return;
    int eB = eA + Ehalf;
    bool hasB = (eB < E);
    int lane = threadIdx.x & 63;
    int base = lane & ~3;

    int sA = src[eA], dA = dst[eA];
    int sB = 0, dB = 0;
    if (hasB) { sB = src[eB]; dB = dst[eB]; }

    int pA = 0, pB = 0;
    if (hh == 0) {
        pA = atomicAdd(&rowptr[dA], 1);
        if (hasB) pB = atomicAdd(&rowptr[dB], 1);
    }

    // Issue all gathers up front for MLP.
    const float4* krA = (const float4*)(k16 + (size_t)sA * FDIM + hh * 16);
    const float4* qrA = (const float4*)(q16 + (size_t)dA * FDIM + hh * 16);
    float4 kA0 = krA[0], kA1 = krA[1];
    float4 qA0 = qrA[0], qA1 = qrA[1];
    float4 kB0, kB1, qB0, qB1;
    if (hasB) {
        const float4* krB = (const float4*)(k16 + (size_t)sB * FDIM + hh * 16);
        const float4* qrB = (const float4*)(q16 + (size_t)dB * FDIM + hh * 16);
        kB0 = krB[0]; kB1 = krB[1];
        qB0 = qrB[0]; qB1 = qrB[1];
    }

    // ---- edge A ----
    {
        float4 kv[2] = { kA0, kA1 }, qv[2] = { qA0, qA1 };
        const __half2* kh = (const __half2*)kv;
        const __half2* qh = (const __half2*)qv;
        float acc = 0.f;
#pragma unroll
        for (int j = 0; j < 8; ++j) {
            float2 kf = __half22float2(kh[j]);
            float2 qf = __half22float2(qh[j]);
            acc = fmaf(kf.x, qf.x, acc);
            acc = fmaf(kf.y, qf.y, acc);
        }
        float m = acc;
        m = fmaxf(m, __shfl_xor(m, 1, 64));
        m = fmaxf(m, __shfl_xor(m, 2, 64));
        float rsq = expf((acc - m) * 0.5f);  // sqrt-domain, in (0,1]
        float x1 = __shfl(rsq, base + 1, 64);
        float x2 = __shfl(rsq, base + 2, 64);
        float x3 = __shfl(rsq, base + 3, 64);
        if (hh == 0) {
            __half2 p01 = __floats2half2_rn(rsq, x1);
            __half2 p23 = __floats2half2_rn(x2, x3);
            uint4 rec;
            rec.x = *(unsigned int*)&p01;
            rec.y = *(unsigned int*)&p23;
            float em = expf(m);
            rec.z = __float_as_uint(em);
            rec.w = (unsigned int)sA;
            recs[pA] = rec;
        }
    }
    // ---- edge B ---- (hasB uniform within the 4-lane group)
    if (hasB) {
        float4 kv[2] = { kB0, kB1 }, qv[2] = { qB0, qB1 };
        const __half2* kh = (const __half2*)kv;
        const __half2* qh = (const __half2*)qv;
        float acc = 0.f;
#pragma unroll
        for (int j = 0; j < 8; ++j) {
            float2 kf = __half22float2(kh[j]);
            float2 qf = __half22float2(qh[j]);
            acc = fmaf(kf.x, qf.x, acc);
            acc = fmaf(kf.y, qf.y, acc);
        }
        float m = acc;
        m = fmaxf(m, __shfl_xor(m, 1, 64));
        m = fmaxf(m, __shfl_xor(m, 2, 64));
        float rsq = expf((acc - m) * 0.5f);
        float x1 = __shfl(rsq, base + 1, 64);
        float x2 = __shfl(rsq, base + 2, 64);
        float x3 = __shfl(rsq, base + 3, 64);
        if (hh == 0) {
            __half2 p01 = __floats2half2_rn(rsq, x1);
            __half2 p23 = __floats2half2_rn(x2, x3);
            uint4 rec;
            rec.x = *(unsigned int*)&p01;
            rec.y = *(unsigned int*)&p23;
            float em = expf(m);
            rec.z = __float_as_uint(em);
            rec.w = (unsigned int)sB;
            recs[pB] = rec;
        }
    }
}

// K4: gather aggregation over CSR rows. One wave per node; lane = feature.
// 16B record -> weight_h = r_h^2 * expm. fp16 h gather. Writes hn (= d_out).
__global__ __launch_bounds__(256) void aggregate_kernel(
    const int* __restrict__ rowend, const uint4* __restrict__ recs,
    const __half* __restrict__ h16, float* __restrict__ hn, int N)
{
    int lane = threadIdx.x & 63;
    int n = blockIdx.x * 4 + (threadIdx.x >> 6);
    if (n >= N) return;
    int end   = rowend[n];
    int start = (n == 0) ? 0 : rowend[n - 1];
    float a0 = 0.f, a1 = 0.f, a2 = 0.f, a3 = 0.f;
    float z0 = 0.f, z1 = 0.f, z2 = 0.f, z3 = 0.f;
    int i = start;
    for (; i + 1 < end; i += 2) {
        uint4 r0 = recs[i];
        uint4 r1 = recs[i + 1];
        int s0 = (int)r0.w;
        int s1 = (int)r1.w;
        float hv0 = __half2float(h16[(size_t)s0 * FDIM + lane]);
        float hv1 = __half2float(h16[(size_t)s1 * FDIM + lane]);
        float em0 = __uint_as_float(r0.z);
        float em1 = __uint_as_float(r1.z);
        float2 e01a = __half22float2(*(__half2*)&r0.x);
        float2 e23a = __half22float2(*(__half2*)&r0.y);
        float2 e01b = __half22float2(*(__half2*)&r1.x);
        float2 e23b = __half22float2(*(__half2*)&r1.y);
        float w0a = e01a.x * e01a.x * em0, w1a = e01a.y * e01a.y * em0;
        float w2a = e23a.x * e23a.x * em0, w3a = e23a.y * e23a.y * em0;
        float w0b = e01b.x * e01b.x * em1, w1b = e01b.y * e01b.y * em1;
        float w2b = e23b.x * e23b.x * em1, w3b = e23b.y * e23b.y * em1;
        a0 = fmaf(w0a, hv0, a0); a1 = fmaf(w1a, hv0, a1);
        a2 = fmaf(w2a, hv0, a2); a3 = fmaf(w3a, hv0, a3);
        z0 += w0a; z1 += w1a; z2 += w2a; z3 += w3a;
        a0 = fmaf(w0b, hv1, a0); a1 = fmaf(w1b, hv1, a1);
        a2 = fmaf(w2b, hv1, a2); a3 = fmaf(w3b, hv1, a3);
        z0 += w0b; z1 += w1b; z2 += w2b; z3 += w3b;
    }
    if (i < end) {
        uint4 r0 = recs[i];
        int s0 = (int)r0.w;
        float hv0 = __half2float(h16[(size_t)s0 * FDIM + lane]);
        float em0 = __uint_as_float(r0.z);
        float2 e01a = __half22float2(*(__half2*)&r0.x);
        float2 e23a = __half22float2(*(__half2*)&r0.y);
        float w0a = e01a.x * e01a.x * em0, w1a = e01a.y * e01a.y * em0;
        float w2a = e23a.x * e23a.x * em0, w3a = e23a.y * e23a.y * em0;
        a0 = fmaf(w0a, hv0, a0); a1 = fmaf(w1a, hv0, a1);
        a2 = fmaf(w2a, hv0, a2); a3 = fmaf(w3a, hv0, a3);
        z0 += w0a; z1 += w1a; z2 += w2a; z3 += w3a;
    }
    float* outr = hn + (size_t)n * (NHEADS * FDIM);
    if (end > start) {
        outr[lane]             = a0 / z0;
        outr[FDIM + lane]      = a1 / z1;
        outr[2 * FDIM + lane]  = a2 / z2;
        outr[3 * FDIM + lane]  = a3 / z3;
    } else {
        outr[lane] = 0.f;
        outr[FDIM + lane] = 0.f;
        outr[2 * FDIM + lane] = 0.f;
        outr[3 * FDIM + lane] = 0.f;
    }
}

// K5: out = hn @ W + b, IN PLACE (hn == out == d_out). Thread = 4 rows x 16 cols.
// In-place safe: the 4 threads sharing a row-group are consecutive lanes of one
// wave, so all row reads complete before any store (lockstep).
__global__ __launch_bounds__(256) void out_kernel(
    const float* hn, const float* __restrict__ W,
    const float* __restrict__ b, float* out, int R)
{
    __shared__ float sW[FDIM * FDIM];
    __shared__ float sb[FDIM];
    for (int i = threadIdx.x; i < FDIM * FDIM; i += 256) sW[i] = W[i];
    if (threadIdx.x < FDIM) sb[threadIdx.x] = b[threadIdx.x];
    __syncthreads();
    int cg = threadIdx.x & 3;
    int rg = threadIdx.x >> 2;
    long base = (long)blockIdx.x * 256 + rg * 4;
    const float4* sW4 = (const float4*)sW;
    const float4* hn4 = (const float4*)hn;
    float acc[4][16];
#pragma unroll
    for (int i = 0; i < 4; ++i)
#pragma unroll
        for (int c = 0; c < 16; ++c) acc[i][c] = sb[cg * 16 + c];

    for (int fs = 0; fs < FDIM; fs += 4) {
        float4 hv[4];
#pragma unroll
        for (int i = 0; i < 4; ++i) {
            long r = base + i; if (r >= R) r = R - 1;
            hv[i] = hn4[r * 16 + (fs >> 2)];
        }
#pragma unroll
        for (int fi = 0; fi < 4; ++fi) {
            int f = fs + fi;
            float4 w0 = sW4[f * 16 + cg * 4 + 0];
            float4 w1 = sW4[f * 16 + cg * 4 + 1];
            float4 w2 = sW4[f * 16 + cg * 4 + 2];
            float4 w3 = sW4[f * 16 + cg * 4 + 3];
#pragma unroll
            for (int i = 0; i < 4; ++i) {
                float hvf = (&hv[i].x)[fi];
                acc[i][0]  = fmaf(hvf, w0.x, acc[i][0]);
                acc[i][1]  = fmaf(hvf, w0.y, acc[i][1]);
                acc[i][2]  = fmaf(hvf, w0.z, acc[i][2]);
                acc[i][3]  = fmaf(hvf, w0.w, acc[i][3]);
                acc[i][4]  = fmaf(hvf, w1.x, acc[i][4]);
                acc[i][5]  = fmaf(hvf, w1.y, acc[i][5]);
                acc[i][6]  = fmaf(hvf, w1.z, acc[i][6]);
                acc[i][7]  = fmaf(hvf, w1.w, acc[i][7]);
                acc[i][8]  = fmaf(hvf, w2.x, acc[i][8]);
                acc[i][9]  = fmaf(hvf, w2.y, acc[i][9]);
                acc[i][10] = fmaf(hvf, w2.z, acc[i][10]);
                acc[i][11] = fmaf(hvf, w2.w, acc[i][11]);
                acc[i][12] = fmaf(hvf, w3.x, acc[i][12]);
                acc[i][13] = fmaf(hvf, w3.y, acc[i][13]);
                acc[i][14] = fmaf(hvf, w3.z, acc[i][14]);
                acc[i][15] = fmaf(hvf, w3.w, acc[i][15]);
            }
        }
    }
#pragma unroll
    for (int i = 0; i < 4; ++i) {
        long r = base + i;
        if (r >= R) continue;
        float4* o = (float4*)(out + (size_t)r * FDIM + cg * 16);
#pragma unroll
        for (int c4 = 0; c4 < 4; ++c4)
            o[c4] = make_float4(acc[i][c4*4], acc[i][c4*4+1], acc[i][c4*4+2], acc[i][c4*4+3]);
    }
}

extern "C" void kernel_launch(void* const* d_in, const int* in_sizes, int n_in,
                              void* d_out, int out_size, void* d_ws, size_t ws_size,
                              hipStream_t stream) {
    const float* h   = (const float*)d_in[0];
    const int*   src = (const int*)d_in[1];
    const int*   dst = (const int*)d_in[2];
    const float* Wk  = (const float*)d_in[3];
    const float* Wq  = (const float*)d_in[4];
    const float* W   = (const float*)d_in[5];
    const float* b   = (const float*)d_in[6];
    float* out = (float*)d_out;

    const int N = in_sizes[0] / FDIM;   // 100000
    const int E = in_sizes[1];          // 1600000

    // Workspace: k16[N*64 h], q16[N*64 h], h16[N*64 h], recs[E uint4],
    //            counts[N], rowptr[N], bsum[256].  (~64 MB)
    __half* k16 = (__half*)d_ws;
    __half* q16 = k16 + (size_t)N * FDIM;
    __half* h16 = q16 + (size_t)N * FDIM;
    uint4* recs = (uint4*)(h16 + (size_t)N * FDIM);
    int* counts = (int*)(recs + (size_t)E);
    int* rowptr = counts + N;
    int* bsum   = rowptr + N;

    const int NBLK = (N + 1023) / 1024;            // 98
    const int KQB  = (N + 127) / 128;              // 782
    const int H2B  = ((N * FDIM / 8) + 255) / 256; // 3125
    const int HIB  = (E + 255) / 256;              // 6250
    const int Ehalf = (E + 1) >> 1;

    hipMemsetAsync(counts, 0, (size_t)N * sizeof(int), stream);

    fused_pre_kernel<<<KQB + H2B + HIB, 256, 0, stream>>>(
        h, Wk, Wq, k16, q16, h16, dst, counts, N, E, KQB, H2B);
    scan1_kernel<<<NBLK, 256, 0, stream>>>(counts, rowptr, bsum, N);
    scan2_kernel<<<1, 256, 0, stream>>>(bsum, NBLK);
    scan3_kernel<<<(N + 255) / 256, 256, 0, stream>>>(rowptr, bsum, N);
    score_scatter_kernel<<<(Ehalf * NHEADS + 255) / 256, 256, 0, stream>>>(
        src, dst, rowptr, k16, q16, recs, E);
    aggregate_kernel<<<(N + 3) / 4, 256, 0, stream>>>(rowptr, recs, h16, out, N);
    out_kernel<<<(N * NHEADS + 255) / 256, 256, 0, stream>>>(out, W, b, out, N * NHEADS);
}